// Round 1
// baseline (1384.940 us; speedup 1.0000x reference)
//
#include <hip/hip_runtime.h>

#define N_NODES 100000
#define N_EDGES 1600000
#define DFEAT   128
#define NGRAPH  64
#define EPSV    1e-5f

// ---------------------------------------------------------------------------
// init: deg=1.0 (the +1.0 in reference), counters/stats/pool buffers = 0
// ---------------------------------------------------------------------------
__global__ void init_kernel(float* __restrict__ degv, int* __restrict__ cnt,
                            int* __restrict__ fillc, float* __restrict__ stats0,
                            float* __restrict__ stats1, float* __restrict__ gsum,
                            float* __restrict__ gcntf) {
    int i = blockIdx.x * 256 + threadIdx.x;
    if (i < N_NODES) { degv[i] = 1.0f; cnt[i] = 0; fillc[i] = 0; }
    if (i < 256)  { stats0[i] = 0.f; stats1[i] = 0.f; }
    if (i < NGRAPH * DFEAT) gsum[i] = 0.f;
    if (i < NGRAPH) gcntf[i] = 0.f;
}

// ---------------------------------------------------------------------------
// deg[dst] += w ; cnt[dst] += 1
// ---------------------------------------------------------------------------
__global__ void edge_deg_kernel(const int* __restrict__ ei, const float* __restrict__ ea,
                                float* __restrict__ degv, int* __restrict__ cnt) {
    int e = blockIdx.x * 256 + threadIdx.x;
    if (e >= N_EDGES) return;
    int d = ei[N_EDGES + e];
    float w = ea[2 * e + 1];
    atomicAdd(&degv[d], w);
    atomicAdd(&cnt[d], 1);
}

// deg -> dinv in place (deg >= 1 always)
__global__ void dinv_kernel(float* __restrict__ degv) {
    int i = blockIdx.x * 256 + threadIdx.x;
    if (i < N_NODES) degv[i] = rsqrtf(degv[i]);
}

// ---------------------------------------------------------------------------
// exclusive scan of cnt[0..N) -> rowptr[0..N], single 1024-thread block
// ---------------------------------------------------------------------------
__global__ __launch_bounds__(1024) void scan_kernel(const int* __restrict__ cnt,
                                                    int* __restrict__ rowptr) {
    __shared__ int sums[1024];
    const int CH = (N_NODES + 1023) / 1024;  // 98
    int t = threadIdx.x;
    int beg = t * CH;
    int end = beg + CH < N_NODES ? beg + CH : N_NODES;
    int s = 0;
    for (int i = beg; i < end; ++i) s += cnt[i];
    sums[t] = s;
    __syncthreads();
    for (int off = 1; off < 1024; off <<= 1) {
        int v = (t >= off) ? sums[t - off] : 0;
        __syncthreads();
        sums[t] += v;
        __syncthreads();
    }
    int pre = (t == 0) ? 0 : sums[t - 1];
    for (int i = beg; i < end; ++i) { rowptr[i] = pre; pre += cnt[i]; }
    if (t == 1023) rowptr[N_NODES] = pre;   // == E
}

// ---------------------------------------------------------------------------
// fill CSR: col[pos]=src, val[pos]=dinv[src]*w*dinv[dst]
// ---------------------------------------------------------------------------
__global__ void fill_kernel(const int* __restrict__ ei, const float* __restrict__ ea,
                            const float* __restrict__ degv, const int* __restrict__ rowptr,
                            int* __restrict__ fillc, int* __restrict__ colIdx,
                            float* __restrict__ valv) {
    int e = blockIdx.x * 256 + threadIdx.x;
    if (e >= N_EDGES) return;
    int s = ei[e], d = ei[N_EDGES + e];
    float w = ea[2 * e + 1];
    float nrm = degv[s] * w * degv[d];
    int pos = rowptr[d] + atomicAdd(&fillc[d], 1);
    colIdx[pos] = s;
    valv[pos] = nrm;
}

// ---------------------------------------------------------------------------
// GEMM: Out[n x 128] = f(X) @ W (+bias)(+relu), f = optional per-col BN scale/shift
// block: 256 threads, tile 64 rows x 128 cols, thread tile 4x8
// ---------------------------------------------------------------------------
__global__ __launch_bounds__(256) void gemm128_kernel(
    const float* __restrict__ X, const float* __restrict__ W,
    float* __restrict__ Out, const float* __restrict__ bnp,
    const float* __restrict__ bias, int do_relu) {
    __shared__ float Xs[64][128];   // 32 KB
    __shared__ float Ws[32][128];   // 16 KB
    const int tid = threadIdx.x;
    const int tc = tid & 15;        // 0..15 -> col group of 8
    const int tr = tid >> 4;        // 0..15 -> row group of 4
    const int rb = blockIdx.x * 64;

    // stage X tile (BN applied on load)
#pragma unroll
    for (int it = 0; it < 8; ++it) {
        int flat = it * 1024 + tid * 4;
        int r = flat >> 7;
        int k = flat & 127;
        float4 v;
        if (rb + r < N_NODES) {
            v = *(const float4*)&X[(size_t)(rb + r) * 128 + k];
            if (bnp) {
                v.x = v.x * bnp[k]     + bnp[128 + k];
                v.y = v.y * bnp[k + 1] + bnp[128 + k + 1];
                v.z = v.z * bnp[k + 2] + bnp[128 + k + 2];
                v.w = v.w * bnp[k + 3] + bnp[128 + k + 3];
            }
        } else {
            v = make_float4(0.f, 0.f, 0.f, 0.f);
        }
        *(float4*)&Xs[r][k] = v;
    }

    float acc[4][8];
#pragma unroll
    for (int i = 0; i < 4; ++i)
#pragma unroll
        for (int j = 0; j < 8; ++j) acc[i][j] = 0.f;

    for (int kb = 0; kb < 128; kb += 32) {
        __syncthreads();
#pragma unroll
        for (int it = 0; it < 4; ++it) {
            int flat = it * 1024 + tid * 4;
            int kk = flat >> 7;
            int c = flat & 127;
            *(float4*)&Ws[kk][c] = *(const float4*)&W[(size_t)(kb + kk) * 128 + c];
        }
        __syncthreads();
#pragma unroll 4
        for (int kk = 0; kk < 32; ++kk) {
            float a0 = Xs[tr * 4 + 0][kb + kk];
            float a1 = Xs[tr * 4 + 1][kb + kk];
            float a2 = Xs[tr * 4 + 2][kb + kk];
            float a3 = Xs[tr * 4 + 3][kb + kk];
            float4 b0 = *(const float4*)&Ws[kk][tc * 8];
            float4 b1 = *(const float4*)&Ws[kk][tc * 8 + 4];
            float bv[8] = {b0.x, b0.y, b0.z, b0.w, b1.x, b1.y, b1.z, b1.w};
            float av[4] = {a0, a1, a2, a3};
#pragma unroll
            for (int i = 0; i < 4; ++i)
#pragma unroll
                for (int j = 0; j < 8; ++j)
                    acc[i][j] = fmaf(av[i], bv[j], acc[i][j]);
        }
    }

#pragma unroll
    for (int i = 0; i < 4; ++i) {
        int row = rb + tr * 4 + i;
        if (row >= N_NODES) continue;
        int c0 = tc * 8;
        float o[8];
#pragma unroll
        for (int j = 0; j < 8; ++j) {
            o[j] = acc[i][j];
            if (bias) o[j] += bias[c0 + j];
            if (do_relu) o[j] = fmaxf(o[j], 0.f);
        }
        *(float4*)&Out[(size_t)row * 128 + c0]     = make_float4(o[0], o[1], o[2], o[3]);
        *(float4*)&Out[(size_t)row * 128 + c0 + 4] = make_float4(o[4], o[5], o[6], o[7]);
    }
}

// ---------------------------------------------------------------------------
// aggregation + self term + bias + relu + BN-stats accumulation
// 1 wave per row (lane = feature, 2 features/lane), 4 waves/block, 16 rows/wave
// ---------------------------------------------------------------------------
__global__ __launch_bounds__(256) void agg_relu_kernel(
    const float* __restrict__ H, const int* __restrict__ rowptr,
    const int* __restrict__ colIdx, const float* __restrict__ valv,
    const float* __restrict__ degv /* = dinv */, const float* __restrict__ bias,
    float* __restrict__ out, float* __restrict__ stats) {
    __shared__ float red[1024];
    const int tid = threadIdx.x;
    const int wv = tid >> 6;
    const int lane = tid & 63;
    const int rowbase = blockIdx.x * 64 + wv * 16;
    const float b0 = bias[lane], b1 = bias[lane + 64];
    float s0 = 0.f, q0 = 0.f, s1 = 0.f, q1 = 0.f;
    for (int r = 0; r < 16; ++r) {
        int i = rowbase + r;
        if (i >= N_NODES) break;
        int beg = rowptr[i], end = rowptr[i + 1];
        float a0 = 0.f, a1 = 0.f;
        for (int j = beg; j < end; ++j) {
            int sidx = colIdx[j];
            float v = valv[j];
            const float* hp = &H[(size_t)sidx * 128];
            a0 = fmaf(v, hp[lane], a0);
            a1 = fmaf(v, hp[lane + 64], a1);
        }
        float di = degv[i];
        float dd = di * di;
        const float* hs = &H[(size_t)i * 128];
        a0 = fmaf(dd, hs[lane], a0) + b0;
        a1 = fmaf(dd, hs[lane + 64], a1) + b1;
        a0 = fmaxf(a0, 0.f);
        a1 = fmaxf(a1, 0.f);
        out[(size_t)i * 128 + lane] = a0;
        out[(size_t)i * 128 + 64 + lane] = a1;
        s0 += a0; q0 += a0 * a0; s1 += a1; q1 += a1 * a1;
    }
    red[wv * 128 + lane] = s0;
    red[wv * 128 + 64 + lane] = s1;
    red[512 + wv * 128 + lane] = q0;
    red[512 + wv * 128 + 64 + lane] = q1;
    __syncthreads();
    if (tid < 128) {
        float ts = red[tid] + red[128 + tid] + red[256 + tid] + red[384 + tid];
        float tq = red[512 + tid] + red[640 + tid] + red[768 + tid] + red[896 + tid];
        atomicAdd(&stats[tid], ts);
        atomicAdd(&stats[128 + tid], tq);
    }
}

// stats -> per-feature scale/shift
__global__ void bn_finalize_kernel(const float* __restrict__ stats,
                                   const float* __restrict__ gamma,
                                   const float* __restrict__ beta,
                                   float* __restrict__ bnp) {
    int f = threadIdx.x;
    float mean = stats[f] / (float)N_NODES;
    float var = stats[128 + f] / (float)N_NODES - mean * mean;
    float sc = gamma[f] * rsqrtf(var + EPSV);
    bnp[f] = sc;
    bnp[128 + f] = beta[f] - mean * sc;
}

// ---------------------------------------------------------------------------
// pooling: batch is sorted; run-length accumulate, flush on graph change
// block: 128 threads (thread = feature), 512 rows per block
// ---------------------------------------------------------------------------
__global__ __launch_bounds__(128) void pool_kernel(const float* __restrict__ h,
                                                   const int* __restrict__ batch,
                                                   float* __restrict__ gsum,
                                                   float* __restrict__ gcntf) {
    const int f = threadIdx.x;
    const int base = blockIdx.x * 512;
    const int end = (base + 512 < N_NODES) ? base + 512 : N_NODES;
    int cur = batch[base];
    float sum = 0.f, cnt = 0.f;
    for (int r = base; r < end; ++r) {
        int g = batch[r];
        if (g != cur) {
            atomicAdd(&gsum[cur * 128 + f], sum);
            if (f == 0) atomicAdd(&gcntf[cur], cnt);
            sum = 0.f; cnt = 0.f; cur = g;
        }
        sum += h[(size_t)r * 128 + f];
        cnt += 1.f;
    }
    atomicAdd(&gsum[cur * 128 + f], sum);
    if (f == 0) atomicAdd(&gcntf[cur], cnt);
}

__global__ void reps_kernel(const float* __restrict__ gsum,
                            const float* __restrict__ gcntf,
                            float* __restrict__ out_reps) {
    int i = blockIdx.x * 256 + threadIdx.x;
    if (i < NGRAPH * 128) {
        int g = i >> 7;
        out_reps[i] = gsum[i] / fmaxf(gcntf[g], 1.0f);
    }
}

// logits = relu(reps @ Wc1 + bc1) @ Wc2 + bc2, one block per graph
__global__ __launch_bounds__(128) void logits_kernel(
    const float* __restrict__ reps, const float* __restrict__ Wc1,
    const float* __restrict__ bc1, const float* __restrict__ Wc2,
    const float* __restrict__ bc2, float* __restrict__ out_logits) {
    __shared__ float repS[128];
    __shared__ float tmp[128];
    int g = blockIdx.x, t = threadIdx.x;
    repS[t] = reps[(size_t)g * 128 + t];
    __syncthreads();
    float acc = bc1[t];
    for (int k = 0; k < 128; ++k) acc = fmaf(repS[k], Wc1[k * 128 + t], acc);
    tmp[t] = fmaxf(acc, 0.f);
    __syncthreads();
    if (t < 2) {
        float a = bc2[t];
        for (int k = 0; k < 128; ++k) a = fmaf(tmp[k], Wc2[k * 2 + t], a);
        out_logits[g * 2 + t] = a;
    }
}

// ---------------------------------------------------------------------------
extern "C" void kernel_launch(void* const* d_in, const int* in_sizes, int n_in,
                              void* d_out, int out_size, void* d_ws, size_t ws_size,
                              hipStream_t stream) {
    const float* x      = (const float*)d_in[0];
    const int*   ei     = (const int*)d_in[1];
    const float* ea     = (const float*)d_in[2];
    const int*   batch  = (const int*)d_in[3];
    const float* Wg0    = (const float*)d_in[4];
    const float* bg0    = (const float*)d_in[5];
    const float* gamma0 = (const float*)d_in[6];
    const float* beta0  = (const float*)d_in[7];
    const float* Wg1    = (const float*)d_in[8];
    const float* bg1    = (const float*)d_in[9];
    const float* gamma1 = (const float*)d_in[10];
    const float* beta1  = (const float*)d_in[11];
    const float* Wl1    = (const float*)d_in[12];
    const float* bl1    = (const float*)d_in[13];
    const float* Wl2    = (const float*)d_in[14];
    const float* bl2    = (const float*)d_in[15];
    const float* Wc1    = (const float*)d_in[16];
    const float* bc1    = (const float*)d_in[17];
    const float* Wc2    = (const float*)d_in[18];
    const float* bc2    = (const float*)d_in[19];

    float* out = (float*)d_out;
    char* ws = (char*)d_ws;
    size_t off = 0;
    auto alloc = [&](size_t bytes) {
        void* p = ws + off;
        off += (bytes + 15) & ~(size_t)15;
        return p;
    };
    float* bufH   = (float*)alloc(sizeof(float) * (size_t)N_NODES * 128);
    float* bufA   = (float*)alloc(sizeof(float) * (size_t)N_NODES * 128);
    float* degv   = (float*)alloc(sizeof(float) * N_NODES);
    float* valv   = (float*)alloc(sizeof(float) * N_EDGES);
    int*   colIdx = (int*)alloc(sizeof(int) * N_EDGES);
    int*   cnt    = (int*)alloc(sizeof(int) * N_NODES);
    int*   fillc  = (int*)alloc(sizeof(int) * N_NODES);
    float* stats0 = (float*)alloc(sizeof(float) * 256);
    float* stats1 = (float*)alloc(sizeof(float) * 256);
    float* bnp0   = (float*)alloc(sizeof(float) * 256);
    float* bnp1   = (float*)alloc(sizeof(float) * 256);
    float* gsum   = (float*)alloc(sizeof(float) * NGRAPH * 128);
    float* gcntf  = (float*)alloc(sizeof(float) * NGRAPH);
    int*   rowptr = (int*)alloc(sizeof(int) * (N_NODES + 1));

    // graph structure (shared by both convs)
    init_kernel<<<(N_NODES + 255) / 256, 256, 0, stream>>>(degv, cnt, fillc, stats0,
                                                           stats1, gsum, gcntf);
    edge_deg_kernel<<<(N_EDGES + 255) / 256, 256, 0, stream>>>(ei, ea, degv, cnt);
    dinv_kernel<<<(N_NODES + 255) / 256, 256, 0, stream>>>(degv);
    scan_kernel<<<1, 1024, 0, stream>>>(cnt, rowptr);
    fill_kernel<<<(N_EDGES + 255) / 256, 256, 0, stream>>>(ei, ea, degv, rowptr, fillc,
                                                           colIdx, valv);

    const int gemm_grid = (N_NODES + 63) / 64;
    // conv0: H0 = x @ Wg0 ; h = relu(agg + bg0) ; BN0 stats
    gemm128_kernel<<<gemm_grid, 256, 0, stream>>>(x, Wg0, bufH, nullptr, nullptr, 0);
    agg_relu_kernel<<<(N_NODES + 63) / 64, 256, 0, stream>>>(bufH, rowptr, colIdx, valv,
                                                             degv, bg0, bufA, stats0);
    bn_finalize_kernel<<<1, 128, 0, stream>>>(stats0, gamma0, beta0, bnp0);
    // conv1: H1 = bn(h) @ Wg1 ; h = relu(agg + bg1) ; BN1 stats
    gemm128_kernel<<<gemm_grid, 256, 0, stream>>>(bufA, Wg1, bufH, bnp0, nullptr, 0);
    agg_relu_kernel<<<(N_NODES + 63) / 64, 256, 0, stream>>>(bufH, rowptr, colIdx, valv,
                                                             degv, bg1, bufA, stats1);
    bn_finalize_kernel<<<1, 128, 0, stream>>>(stats1, gamma1, beta1, bnp1);
    // lin1: relu(bn(h) @ Wl1 + bl1) ; lin2: @ Wl2 + bl2 -> d_out h
    gemm128_kernel<<<gemm_grid, 256, 0, stream>>>(bufA, Wl1, bufH, bnp1, bl1, 1);
    gemm128_kernel<<<gemm_grid, 256, 0, stream>>>(bufH, Wl2, out, nullptr, bl2, 0);
    // pooling + head
    pool_kernel<<<(N_NODES + 511) / 512, 128, 0, stream>>>(out, batch, gsum, gcntf);
    reps_kernel<<<(NGRAPH * 128 + 255) / 256, 256, 0, stream>>>(
        gsum, gcntf, out + (size_t)N_NODES * 128);
    logits_kernel<<<NGRAPH, 128, 0, stream>>>(out + (size_t)N_NODES * 128, Wc1, bc1, Wc2,
                                              bc2, out + (size_t)N_NODES * 128 + NGRAPH * 128);
}

// Round 2
// 1266.483 us; speedup vs baseline: 1.0935x; 1.0935x over previous
//
#include <hip/hip_runtime.h>

#define N_NODES 100000
#define N_EDGES 1600000
#define DFEAT   128
#define NGRAPH  64
#define EPSV    1e-5f

// ---------------------------------------------------------------------------
// init: deg=1.0 (the +1.0 in reference), counters/stats/pool buffers = 0
// ---------------------------------------------------------------------------
__global__ void init_kernel(float* __restrict__ degv, int* __restrict__ cnt,
                            int* __restrict__ fillc, float* __restrict__ stats0,
                            float* __restrict__ stats1, float* __restrict__ gsum,
                            float* __restrict__ gcntf) {
    int i = blockIdx.x * 256 + threadIdx.x;
    if (i < N_NODES) { degv[i] = 1.0f; cnt[i] = 0; fillc[i] = 0; }
    if (i < 256)  { stats0[i] = 0.f; stats1[i] = 0.f; }
    if (i < NGRAPH * DFEAT) gsum[i] = 0.f;
    if (i < NGRAPH) gcntf[i] = 0.f;
}

// ---------------------------------------------------------------------------
// deg[dst] += w ; cnt[dst] += 1
// ---------------------------------------------------------------------------
__global__ void edge_deg_kernel(const int* __restrict__ ei, const float* __restrict__ ea,
                                float* __restrict__ degv, int* __restrict__ cnt) {
    int e = blockIdx.x * 256 + threadIdx.x;
    if (e >= N_EDGES) return;
    int d = ei[N_EDGES + e];
    float w = ea[2 * e + 1];
    atomicAdd(&degv[d], w);
    atomicAdd(&cnt[d], 1);
}

// deg -> dinv in place (deg >= 1 always)
__global__ void dinv_kernel(float* __restrict__ degv) {
    int i = blockIdx.x * 256 + threadIdx.x;
    if (i < N_NODES) degv[i] = rsqrtf(degv[i]);
}

// ---------------------------------------------------------------------------
// exclusive scan of cnt[0..N) -> rowptr[0..N], single 1024-thread block
// ---------------------------------------------------------------------------
__global__ __launch_bounds__(1024) void scan_kernel(const int* __restrict__ cnt,
                                                    int* __restrict__ rowptr) {
    __shared__ int sums[1024];
    const int CH = (N_NODES + 1023) / 1024;  // 98
    int t = threadIdx.x;
    int beg = t * CH;
    int end = beg + CH < N_NODES ? beg + CH : N_NODES;
    int s = 0;
    for (int i = beg; i < end; ++i) s += cnt[i];
    sums[t] = s;
    __syncthreads();
    for (int off = 1; off < 1024; off <<= 1) {
        int v = (t >= off) ? sums[t - off] : 0;
        __syncthreads();
        sums[t] += v;
        __syncthreads();
    }
    int pre = (t == 0) ? 0 : sums[t - 1];
    for (int i = beg; i < end; ++i) { rowptr[i] = pre; pre += cnt[i]; }
    if (t == 1023) rowptr[N_NODES] = pre;   // == E
}

// ---------------------------------------------------------------------------
// fill CSR: col[pos]=src, val[pos]=dinv[src]*w*dinv[dst]
// ---------------------------------------------------------------------------
__global__ void fill_kernel(const int* __restrict__ ei, const float* __restrict__ ea,
                            const float* __restrict__ degv, const int* __restrict__ rowptr,
                            int* __restrict__ fillc, int* __restrict__ colIdx,
                            float* __restrict__ valv) {
    int e = blockIdx.x * 256 + threadIdx.x;
    if (e >= N_EDGES) return;
    int s = ei[e], d = ei[N_EDGES + e];
    float w = ea[2 * e + 1];
    float nrm = degv[s] * w * degv[d];
    int pos = rowptr[d] + atomicAdd(&fillc[d], 1);
    colIdx[pos] = s;
    valv[pos] = nrm;
}

// ---------------------------------------------------------------------------
// GEMM: Out[n x 128] = f(X) @ W (+bias)(+relu), f = optional per-col BN scale/shift
// block: 256 threads, tile 64 rows x 128 cols, thread tile 4x8
// ---------------------------------------------------------------------------
__global__ __launch_bounds__(256) void gemm128_kernel(
    const float* __restrict__ X, const float* __restrict__ W,
    float* __restrict__ Out, const float* __restrict__ bnp,
    const float* __restrict__ bias, int do_relu) {
    __shared__ float Xs[64][128];   // 32 KB
    __shared__ float Ws[32][128];   // 16 KB
    const int tid = threadIdx.x;
    const int tc = tid & 15;        // 0..15 -> col group of 8
    const int tr = tid >> 4;        // 0..15 -> row group of 4
    const int rb = blockIdx.x * 64;

    // stage X tile (BN applied on load)
#pragma unroll
    for (int it = 0; it < 8; ++it) {
        int flat = it * 1024 + tid * 4;
        int r = flat >> 7;
        int k = flat & 127;
        float4 v;
        if (rb + r < N_NODES) {
            v = *(const float4*)&X[(size_t)(rb + r) * 128 + k];
            if (bnp) {
                v.x = v.x * bnp[k]     + bnp[128 + k];
                v.y = v.y * bnp[k + 1] + bnp[128 + k + 1];
                v.z = v.z * bnp[k + 2] + bnp[128 + k + 2];
                v.w = v.w * bnp[k + 3] + bnp[128 + k + 3];
            }
        } else {
            v = make_float4(0.f, 0.f, 0.f, 0.f);
        }
        *(float4*)&Xs[r][k] = v;
    }

    float acc[4][8];
#pragma unroll
    for (int i = 0; i < 4; ++i)
#pragma unroll
        for (int j = 0; j < 8; ++j) acc[i][j] = 0.f;

    for (int kb = 0; kb < 128; kb += 32) {
        __syncthreads();
#pragma unroll
        for (int it = 0; it < 4; ++it) {
            int flat = it * 1024 + tid * 4;
            int kk = flat >> 7;
            int c = flat & 127;
            *(float4*)&Ws[kk][c] = *(const float4*)&W[(size_t)(kb + kk) * 128 + c];
        }
        __syncthreads();
#pragma unroll 4
        for (int kk = 0; kk < 32; ++kk) {
            float a0 = Xs[tr * 4 + 0][kb + kk];
            float a1 = Xs[tr * 4 + 1][kb + kk];
            float a2 = Xs[tr * 4 + 2][kb + kk];
            float a3 = Xs[tr * 4 + 3][kb + kk];
            float4 b0 = *(const float4*)&Ws[kk][tc * 8];
            float4 b1 = *(const float4*)&Ws[kk][tc * 8 + 4];
            float bv[8] = {b0.x, b0.y, b0.z, b0.w, b1.x, b1.y, b1.z, b1.w};
            float av[4] = {a0, a1, a2, a3};
#pragma unroll
            for (int i = 0; i < 4; ++i)
#pragma unroll
                for (int j = 0; j < 8; ++j)
                    acc[i][j] = fmaf(av[i], bv[j], acc[i][j]);
        }
    }

#pragma unroll
    for (int i = 0; i < 4; ++i) {
        int row = rb + tr * 4 + i;
        if (row >= N_NODES) continue;
        int c0 = tc * 8;
        float o[8];
#pragma unroll
        for (int j = 0; j < 8; ++j) {
            o[j] = acc[i][j];
            if (bias) o[j] += bias[c0 + j];
            if (do_relu) o[j] = fmaxf(o[j], 0.f);
        }
        *(float4*)&Out[(size_t)row * 128 + c0]     = make_float4(o[0], o[1], o[2], o[3]);
        *(float4*)&Out[(size_t)row * 128 + c0 + 4] = make_float4(o[4], o[5], o[6], o[7]);
    }
}

// ---------------------------------------------------------------------------
// aggregation + self term + bias + relu + BN-stats accumulation
// 1 wave per row (lane = 2 consecutive features via float2), grid-stride over
// rows with exactly 8192 waves (= machine wave capacity), 4-edge unrolled
// inner loop with independent partial accumulators for memory-level parallelism
// ---------------------------------------------------------------------------
__global__ __launch_bounds__(256) void agg_relu_kernel(
    const float* __restrict__ H, const int* __restrict__ rowptr,
    const int* __restrict__ colIdx, const float* __restrict__ valv,
    const float* __restrict__ dinv, const float* __restrict__ bias,
    float* __restrict__ out, float* __restrict__ stats, int nwaves) {
    __shared__ float red[1024];
    const int tid = threadIdx.x;
    const int wv = tid >> 6;
    const int lane = tid & 63;
    const float2 b2 = ((const float2*)bias)[lane];
    const float2* __restrict__ H2 = (const float2*)H;
    float s0 = 0.f, q0 = 0.f, s1 = 0.f, q1 = 0.f;

    for (int i = blockIdx.x * 4 + wv; i < N_NODES; i += nwaves) {
        int beg = __builtin_amdgcn_readfirstlane(rowptr[i]);
        int end = __builtin_amdgcn_readfirstlane(rowptr[i + 1]);
        float2 p0 = {0.f, 0.f}, p1 = {0.f, 0.f}, p2 = {0.f, 0.f}, p3 = {0.f, 0.f};
        int j = beg;
        for (; j + 4 <= end; j += 4) {
            int c0 = colIdx[j], c1 = colIdx[j + 1], c2 = colIdx[j + 2], c3 = colIdx[j + 3];
            float v0 = valv[j], v1 = valv[j + 1], v2 = valv[j + 2], v3 = valv[j + 3];
            float2 h0 = H2[(size_t)c0 * 64 + lane];
            float2 h1 = H2[(size_t)c1 * 64 + lane];
            float2 h2 = H2[(size_t)c2 * 64 + lane];
            float2 h3 = H2[(size_t)c3 * 64 + lane];
            p0.x = fmaf(v0, h0.x, p0.x); p0.y = fmaf(v0, h0.y, p0.y);
            p1.x = fmaf(v1, h1.x, p1.x); p1.y = fmaf(v1, h1.y, p1.y);
            p2.x = fmaf(v2, h2.x, p2.x); p2.y = fmaf(v2, h2.y, p2.y);
            p3.x = fmaf(v3, h3.x, p3.x); p3.y = fmaf(v3, h3.y, p3.y);
        }
        for (; j < end; ++j) {
            int c = colIdx[j];
            float v = valv[j];
            float2 h0 = H2[(size_t)c * 64 + lane];
            p0.x = fmaf(v, h0.x, p0.x); p0.y = fmaf(v, h0.y, p0.y);
        }
        float di = dinv[i];
        float dd = di * di;
        float2 hs = H2[(size_t)i * 64 + lane];
        float ax = (p0.x + p1.x) + (p2.x + p3.x);
        float ay = (p0.y + p1.y) + (p2.y + p3.y);
        ax = fmaf(dd, hs.x, ax) + b2.x;
        ay = fmaf(dd, hs.y, ay) + b2.y;
        ax = fmaxf(ax, 0.f);
        ay = fmaxf(ay, 0.f);
        ((float2*)out)[(size_t)i * 64 + lane] = make_float2(ax, ay);
        s0 += ax; q0 += ax * ax; s1 += ay; q1 += ay * ay;
    }

    // feature f0 = 2*lane, f1 = 2*lane+1
    red[wv * 128 + 2 * lane]       = s0;
    red[wv * 128 + 2 * lane + 1]   = s1;
    red[512 + wv * 128 + 2 * lane]     = q0;
    red[512 + wv * 128 + 2 * lane + 1] = q1;
    __syncthreads();
    if (tid < 128) {
        float ts = red[tid] + red[128 + tid] + red[256 + tid] + red[384 + tid];
        float tq = red[512 + tid] + red[640 + tid] + red[768 + tid] + red[896 + tid];
        atomicAdd(&stats[tid], ts);
        atomicAdd(&stats[128 + tid], tq);
    }
}

// stats -> per-feature scale/shift
__global__ void bn_finalize_kernel(const float* __restrict__ stats,
                                   const float* __restrict__ gamma,
                                   const float* __restrict__ beta,
                                   float* __restrict__ bnp) {
    int f = threadIdx.x;
    float mean = stats[f] / (float)N_NODES;
    float var = stats[128 + f] / (float)N_NODES - mean * mean;
    float sc = gamma[f] * rsqrtf(var + EPSV);
    bnp[f] = sc;
    bnp[128 + f] = beta[f] - mean * sc;
}

// ---------------------------------------------------------------------------
// pooling: batch is sorted; run-length accumulate, flush on graph change
// block: 128 threads (thread = feature), 512 rows per block
// ---------------------------------------------------------------------------
__global__ __launch_bounds__(128) void pool_kernel(const float* __restrict__ h,
                                                   const int* __restrict__ batch,
                                                   float* __restrict__ gsum,
                                                   float* __restrict__ gcntf) {
    const int f = threadIdx.x;
    const int base = blockIdx.x * 512;
    const int end = (base + 512 < N_NODES) ? base + 512 : N_NODES;
    int cur = batch[base];
    float sum = 0.f, cnt = 0.f;
    for (int r = base; r < end; ++r) {
        int g = batch[r];
        if (g != cur) {
            atomicAdd(&gsum[cur * 128 + f], sum);
            if (f == 0) atomicAdd(&gcntf[cur], cnt);
            sum = 0.f; cnt = 0.f; cur = g;
        }
        sum += h[(size_t)r * 128 + f];
        cnt += 1.f;
    }
    atomicAdd(&gsum[cur * 128 + f], sum);
    if (f == 0) atomicAdd(&gcntf[cur], cnt);
}

__global__ void reps_kernel(const float* __restrict__ gsum,
                            const float* __restrict__ gcntf,
                            float* __restrict__ out_reps) {
    int i = blockIdx.x * 256 + threadIdx.x;
    if (i < NGRAPH * 128) {
        int g = i >> 7;
        out_reps[i] = gsum[i] / fmaxf(gcntf[g], 1.0f);
    }
}

// logits = relu(reps @ Wc1 + bc1) @ Wc2 + bc2, one block per graph
__global__ __launch_bounds__(128) void logits_kernel(
    const float* __restrict__ reps, const float* __restrict__ Wc1,
    const float* __restrict__ bc1, const float* __restrict__ Wc2,
    const float* __restrict__ bc2, float* __restrict__ out_logits) {
    __shared__ float repS[128];
    __shared__ float tmp[128];
    int g = blockIdx.x, t = threadIdx.x;
    repS[t] = reps[(size_t)g * 128 + t];
    __syncthreads();
    float acc = bc1[t];
    for (int k = 0; k < 128; ++k) acc = fmaf(repS[k], Wc1[k * 128 + t], acc);
    tmp[t] = fmaxf(acc, 0.f);
    __syncthreads();
    if (t < 2) {
        float a = bc2[t];
        for (int k = 0; k < 128; ++k) a = fmaf(tmp[k], Wc2[k * 2 + t], a);
        out_logits[g * 2 + t] = a;
    }
}

// ---------------------------------------------------------------------------
extern "C" void kernel_launch(void* const* d_in, const int* in_sizes, int n_in,
                              void* d_out, int out_size, void* d_ws, size_t ws_size,
                              hipStream_t stream) {
    const float* x      = (const float*)d_in[0];
    const int*   ei     = (const int*)d_in[1];
    const float* ea     = (const float*)d_in[2];
    const int*   batch  = (const int*)d_in[3];
    const float* Wg0    = (const float*)d_in[4];
    const float* bg0    = (const float*)d_in[5];
    const float* gamma0 = (const float*)d_in[6];
    const float* beta0  = (const float*)d_in[7];
    const float* Wg1    = (const float*)d_in[8];
    const float* bg1    = (const float*)d_in[9];
    const float* gamma1 = (const float*)d_in[10];
    const float* beta1  = (const float*)d_in[11];
    const float* Wl1    = (const float*)d_in[12];
    const float* bl1    = (const float*)d_in[13];
    const float* Wl2    = (const float*)d_in[14];
    const float* bl2    = (const float*)d_in[15];
    const float* Wc1    = (const float*)d_in[16];
    const float* bc1    = (const float*)d_in[17];
    const float* Wc2    = (const float*)d_in[18];
    const float* bc2    = (const float*)d_in[19];

    float* out = (float*)d_out;
    char* ws = (char*)d_ws;
    size_t off = 0;
    auto alloc = [&](size_t bytes) {
        void* p = ws + off;
        off += (bytes + 15) & ~(size_t)15;
        return p;
    };
    float* bufH   = (float*)alloc(sizeof(float) * (size_t)N_NODES * 128);
    float* bufA   = (float*)alloc(sizeof(float) * (size_t)N_NODES * 128);
    float* degv   = (float*)alloc(sizeof(float) * N_NODES);
    float* valv   = (float*)alloc(sizeof(float) * N_EDGES);
    int*   colIdx = (int*)alloc(sizeof(int) * N_EDGES);
    int*   cnt    = (int*)alloc(sizeof(int) * N_NODES);
    int*   fillc  = (int*)alloc(sizeof(int) * N_NODES);
    float* stats0 = (float*)alloc(sizeof(float) * 256);
    float* stats1 = (float*)alloc(sizeof(float) * 256);
    float* bnp0   = (float*)alloc(sizeof(float) * 256);
    float* bnp1   = (float*)alloc(sizeof(float) * 256);
    float* gsum   = (float*)alloc(sizeof(float) * NGRAPH * 128);
    float* gcntf  = (float*)alloc(sizeof(float) * NGRAPH);
    int*   rowptr = (int*)alloc(sizeof(int) * (N_NODES + 1));

    // graph structure (shared by both convs)
    init_kernel<<<(N_NODES + 255) / 256, 256, 0, stream>>>(degv, cnt, fillc, stats0,
                                                           stats1, gsum, gcntf);
    edge_deg_kernel<<<(N_EDGES + 255) / 256, 256, 0, stream>>>(ei, ea, degv, cnt);
    dinv_kernel<<<(N_NODES + 255) / 256, 256, 0, stream>>>(degv);
    scan_kernel<<<1, 1024, 0, stream>>>(cnt, rowptr);
    fill_kernel<<<(N_EDGES + 255) / 256, 256, 0, stream>>>(ei, ea, degv, rowptr, fillc,
                                                           colIdx, valv);

    const int gemm_grid = (N_NODES + 63) / 64;
    const int agg_blocks = 2048;            // 8192 waves = full machine
    const int agg_nwaves = agg_blocks * 4;
    // conv0: H0 = x @ Wg0 ; h = relu(agg + bg0) ; BN0 stats
    gemm128_kernel<<<gemm_grid, 256, 0, stream>>>(x, Wg0, bufH, nullptr, nullptr, 0);
    agg_relu_kernel<<<agg_blocks, 256, 0, stream>>>(bufH, rowptr, colIdx, valv,
                                                    degv, bg0, bufA, stats0, agg_nwaves);
    bn_finalize_kernel<<<1, 128, 0, stream>>>(stats0, gamma0, beta0, bnp0);
    // conv1: H1 = bn(h) @ Wg1 ; h = relu(agg + bg1) ; BN1 stats
    gemm128_kernel<<<gemm_grid, 256, 0, stream>>>(bufA, Wg1, bufH, bnp0, nullptr, 0);
    agg_relu_kernel<<<agg_blocks, 256, 0, stream>>>(bufH, rowptr, colIdx, valv,
                                                    degv, bg1, bufA, stats1, agg_nwaves);
    bn_finalize_kernel<<<1, 128, 0, stream>>>(stats1, gamma1, beta1, bnp1);
    // lin1: relu(bn(h) @ Wl1 + bl1) ; lin2: @ Wl2 + bl2 -> d_out h
    gemm128_kernel<<<gemm_grid, 256, 0, stream>>>(bufA, Wl1, bufH, bnp1, bl1, 1);
    gemm128_kernel<<<gemm_grid, 256, 0, stream>>>(bufH, Wl2, out, nullptr, bl2, 0);
    // pooling + head
    pool_kernel<<<(N_NODES + 511) / 512, 128, 0, stream>>>(out, batch, gsum, gcntf);
    reps_kernel<<<(NGRAPH * 128 + 255) / 256, 256, 0, stream>>>(
        gsum, gcntf, out + (size_t)N_NODES * 128);
    logits_kernel<<<NGRAPH, 128, 0, stream>>>(out + (size_t)N_NODES * 128, Wc1, bc1, Wc2,
                                              bc2, out + (size_t)N_NODES * 128 + NGRAPH * 128);
}

// Round 3
// 1122.183 us; speedup vs baseline: 1.2341x; 1.1286x over previous
//
#include <hip/hip_runtime.h>

#define N_NODES 100000
#define N_EDGES 1600000
#define DFEAT   128
#define NGRAPH  64
#define EPSV    1e-5f
#define SCAN_BLOCKS ((N_NODES + 255) / 256)   // 391

// ---------------------------------------------------------------------------
// init: deg=1.0 (the +1.0 in reference), counters/stats/pool buffers = 0
// ---------------------------------------------------------------------------
__global__ void init_kernel(float* __restrict__ degv, int* __restrict__ cnt,
                            int* __restrict__ fillc, float* __restrict__ stats0,
                            float* __restrict__ stats1, float* __restrict__ gsum,
                            float* __restrict__ gcntf) {
    int i = blockIdx.x * 256 + threadIdx.x;
    if (i < N_NODES) { degv[i] = 1.0f; cnt[i] = 0; fillc[i] = 0; }
    if (i < 256)  { stats0[i] = 0.f; stats1[i] = 0.f; }
    if (i < NGRAPH * DFEAT) gsum[i] = 0.f;
    if (i < NGRAPH) gcntf[i] = 0.f;
}

// ---------------------------------------------------------------------------
// deg[dst] += w ; cnt[dst] += 1
// ---------------------------------------------------------------------------
__global__ void edge_deg_kernel(const int* __restrict__ ei, const float* __restrict__ ea,
                                float* __restrict__ degv, int* __restrict__ cnt) {
    int e = blockIdx.x * 256 + threadIdx.x;
    if (e >= N_EDGES) return;
    int d = ei[N_EDGES + e];
    float w = ea[2 * e + 1];
    atomicAdd(&degv[d], w);
    atomicAdd(&cnt[d], 1);
}

// deg -> dinv in place (deg >= 1 always)
__global__ void dinv_kernel(float* __restrict__ degv) {
    int i = blockIdx.x * 256 + threadIdx.x;
    if (i < N_NODES) degv[i] = rsqrtf(degv[i]);
}

// ---------------------------------------------------------------------------
// 3-phase device-wide exclusive scan of cnt -> rowptr
// ---------------------------------------------------------------------------
__global__ __launch_bounds__(256) void scan1_kernel(const int* __restrict__ cnt,
                                                    int* __restrict__ blockSum) {
    __shared__ int lds[256];
    int i = blockIdx.x * 256 + threadIdx.x;
    int t = threadIdx.x;
    lds[t] = (i < N_NODES) ? cnt[i] : 0;
    __syncthreads();
    for (int off = 128; off > 0; off >>= 1) {
        if (t < off) lds[t] += lds[t + off];
        __syncthreads();
    }
    if (t == 0) blockSum[blockIdx.x] = lds[0];
}

__global__ __launch_bounds__(512) void scan2_kernel(int* __restrict__ blockSum) {
    __shared__ int lds[512];
    int t = threadIdx.x;
    int v = (t < SCAN_BLOCKS) ? blockSum[t] : 0;
    lds[t] = v;
    __syncthreads();
    for (int off = 1; off < 512; off <<= 1) {
        int u = (t >= off) ? lds[t - off] : 0;
        __syncthreads();
        lds[t] += u;
        __syncthreads();
    }
    if (t < SCAN_BLOCKS) blockSum[t] = lds[t] - v;  // exclusive
}

__global__ __launch_bounds__(256) void scan3_kernel(const int* __restrict__ cnt,
                                                    const int* __restrict__ blockSum,
                                                    int* __restrict__ rowptr) {
    __shared__ int lds[256];
    int i = blockIdx.x * 256 + threadIdx.x;
    int t = threadIdx.x;
    int v = (i < N_NODES) ? cnt[i] : 0;
    lds[t] = v;
    __syncthreads();
    for (int off = 1; off < 256; off <<= 1) {
        int u = (t >= off) ? lds[t - off] : 0;
        __syncthreads();
        lds[t] += u;
        __syncthreads();
    }
    if (i < N_NODES) rowptr[i] = blockSum[blockIdx.x] + lds[t] - v;
    if (i == 0) rowptr[N_NODES] = N_EDGES;
}

// ---------------------------------------------------------------------------
// fill CSR: col[pos]=src, val[pos]=dinv[src]*w*dinv[dst]
// ---------------------------------------------------------------------------
__global__ void fill_kernel(const int* __restrict__ ei, const float* __restrict__ ea,
                            const float* __restrict__ degv, const int* __restrict__ rowptr,
                            int* __restrict__ fillc, int* __restrict__ colIdx,
                            float* __restrict__ valv) {
    int e = blockIdx.x * 256 + threadIdx.x;
    if (e >= N_EDGES) return;
    int s = ei[e], d = ei[N_EDGES + e];
    float w = ea[2 * e + 1];
    float nrm = degv[s] * w * degv[d];
    int pos = rowptr[d] + atomicAdd(&fillc[d], 1);
    colIdx[pos] = s;
    valv[pos] = nrm;
}

// ---------------------------------------------------------------------------
// GEMM: Out[n x 128] = f(X) @ W (+bias)(+relu), f = optional per-col BN scale/shift
// block: 256 threads, tile 64 rows x 128 cols, thread tile 4x8
// ---------------------------------------------------------------------------
__global__ __launch_bounds__(256) void gemm128_kernel(
    const float* __restrict__ X, const float* __restrict__ W,
    float* __restrict__ Out, const float* __restrict__ bnp,
    const float* __restrict__ bias, int do_relu) {
    __shared__ float Xs[64][128];   // 32 KB
    __shared__ float Ws[32][128];   // 16 KB
    const int tid = threadIdx.x;
    const int tc = tid & 15;        // 0..15 -> col group of 8
    const int tr = tid >> 4;        // 0..15 -> row group of 4
    const int rb = blockIdx.x * 64;

    // stage X tile (BN applied on load)
#pragma unroll
    for (int it = 0; it < 8; ++it) {
        int flat = it * 1024 + tid * 4;
        int r = flat >> 7;
        int k = flat & 127;
        float4 v;
        if (rb + r < N_NODES) {
            v = *(const float4*)&X[(size_t)(rb + r) * 128 + k];
            if (bnp) {
                v.x = v.x * bnp[k]     + bnp[128 + k];
                v.y = v.y * bnp[k + 1] + bnp[128 + k + 1];
                v.z = v.z * bnp[k + 2] + bnp[128 + k + 2];
                v.w = v.w * bnp[k + 3] + bnp[128 + k + 3];
            }
        } else {
            v = make_float4(0.f, 0.f, 0.f, 0.f);
        }
        *(float4*)&Xs[r][k] = v;
    }

    float acc[4][8];
#pragma unroll
    for (int i = 0; i < 4; ++i)
#pragma unroll
        for (int j = 0; j < 8; ++j) acc[i][j] = 0.f;

    for (int kb = 0; kb < 128; kb += 32) {
        __syncthreads();
#pragma unroll
        for (int it = 0; it < 4; ++it) {
            int flat = it * 1024 + tid * 4;
            int kk = flat >> 7;
            int c = flat & 127;
            *(float4*)&Ws[kk][c] = *(const float4*)&W[(size_t)(kb + kk) * 128 + c];
        }
        __syncthreads();
#pragma unroll 4
        for (int kk = 0; kk < 32; ++kk) {
            float a0 = Xs[tr * 4 + 0][kb + kk];
            float a1 = Xs[tr * 4 + 1][kb + kk];
            float a2 = Xs[tr * 4 + 2][kb + kk];
            float a3 = Xs[tr * 4 + 3][kb + kk];
            float4 b0 = *(const float4*)&Ws[kk][tc * 8];
            float4 b1 = *(const float4*)&Ws[kk][tc * 8 + 4];
            float bv[8] = {b0.x, b0.y, b0.z, b0.w, b1.x, b1.y, b1.z, b1.w};
            float av[4] = {a0, a1, a2, a3};
#pragma unroll
            for (int i = 0; i < 4; ++i)
#pragma unroll
                for (int j = 0; j < 8; ++j)
                    acc[i][j] = fmaf(av[i], bv[j], acc[i][j]);
        }
    }

#pragma unroll
    for (int i = 0; i < 4; ++i) {
        int row = rb + tr * 4 + i;
        if (row >= N_NODES) continue;
        int c0 = tc * 8;
        float o[8];
#pragma unroll
        for (int j = 0; j < 8; ++j) {
            o[j] = acc[i][j];
            if (bias) o[j] += bias[c0 + j];
            if (do_relu) o[j] = fmaxf(o[j], 0.f);
        }
        *(float4*)&Out[(size_t)row * 128 + c0]     = make_float4(o[0], o[1], o[2], o[3]);
        *(float4*)&Out[(size_t)row * 128 + c0 + 4] = make_float4(o[4], o[5], o[6], o[7]);
    }
}

// ---------------------------------------------------------------------------
// aggregation + self term + bias + relu + BN-stats accumulation
// 1 wave per row (lane = 2 consecutive features via float2), grid-stride over
// rows with exactly 8192 waves, 4-edge unrolled inner loop for MLP
// ---------------------------------------------------------------------------
__global__ __launch_bounds__(256) void agg_relu_kernel(
    const float* __restrict__ H, const int* __restrict__ rowptr,
    const int* __restrict__ colIdx, const float* __restrict__ valv,
    const float* __restrict__ dinv, const float* __restrict__ bias,
    float* __restrict__ out, float* __restrict__ stats, int nwaves) {
    __shared__ float red[1024];
    const int tid = threadIdx.x;
    const int wv = tid >> 6;
    const int lane = tid & 63;
    const float2 b2 = ((const float2*)bias)[lane];
    const float2* __restrict__ H2 = (const float2*)H;
    float s0 = 0.f, q0 = 0.f, s1 = 0.f, q1 = 0.f;

    for (int i = blockIdx.x * 4 + wv; i < N_NODES; i += nwaves) {
        int beg = __builtin_amdgcn_readfirstlane(rowptr[i]);
        int end = __builtin_amdgcn_readfirstlane(rowptr[i + 1]);
        float2 p0 = {0.f, 0.f}, p1 = {0.f, 0.f}, p2 = {0.f, 0.f}, p3 = {0.f, 0.f};
        int j = beg;
        for (; j + 4 <= end; j += 4) {
            int c0 = colIdx[j], c1 = colIdx[j + 1], c2 = colIdx[j + 2], c3 = colIdx[j + 3];
            float v0 = valv[j], v1 = valv[j + 1], v2 = valv[j + 2], v3 = valv[j + 3];
            float2 h0 = H2[(size_t)c0 * 64 + lane];
            float2 h1 = H2[(size_t)c1 * 64 + lane];
            float2 h2 = H2[(size_t)c2 * 64 + lane];
            float2 h3 = H2[(size_t)c3 * 64 + lane];
            p0.x = fmaf(v0, h0.x, p0.x); p0.y = fmaf(v0, h0.y, p0.y);
            p1.x = fmaf(v1, h1.x, p1.x); p1.y = fmaf(v1, h1.y, p1.y);
            p2.x = fmaf(v2, h2.x, p2.x); p2.y = fmaf(v2, h2.y, p2.y);
            p3.x = fmaf(v3, h3.x, p3.x); p3.y = fmaf(v3, h3.y, p3.y);
        }
        for (; j < end; ++j) {
            int c = colIdx[j];
            float v = valv[j];
            float2 h0 = H2[(size_t)c * 64 + lane];
            p0.x = fmaf(v, h0.x, p0.x); p0.y = fmaf(v, h0.y, p0.y);
        }
        float di = dinv[i];
        float dd = di * di;
        float2 hs = H2[(size_t)i * 64 + lane];
        float ax = (p0.x + p1.x) + (p2.x + p3.x);
        float ay = (p0.y + p1.y) + (p2.y + p3.y);
        ax = fmaf(dd, hs.x, ax) + b2.x;
        ay = fmaf(dd, hs.y, ay) + b2.y;
        ax = fmaxf(ax, 0.f);
        ay = fmaxf(ay, 0.f);
        ((float2*)out)[(size_t)i * 64 + lane] = make_float2(ax, ay);
        s0 += ax; q0 += ax * ax; s1 += ay; q1 += ay * ay;
    }

    // feature f0 = 2*lane, f1 = 2*lane+1
    red[wv * 128 + 2 * lane]       = s0;
    red[wv * 128 + 2 * lane + 1]   = s1;
    red[512 + wv * 128 + 2 * lane]     = q0;
    red[512 + wv * 128 + 2 * lane + 1] = q1;
    __syncthreads();
    if (tid < 128) {
        float ts = red[tid] + red[128 + tid] + red[256 + tid] + red[384 + tid];
        float tq = red[512 + tid] + red[640 + tid] + red[768 + tid] + red[896 + tid];
        atomicAdd(&stats[tid], ts);
        atomicAdd(&stats[128 + tid], tq);
    }
}

// stats -> per-feature scale/shift
__global__ void bn_finalize_kernel(const float* __restrict__ stats,
                                   const float* __restrict__ gamma,
                                   const float* __restrict__ beta,
                                   float* __restrict__ bnp) {
    int f = threadIdx.x;
    float mean = stats[f] / (float)N_NODES;
    float var = stats[128 + f] / (float)N_NODES - mean * mean;
    float sc = gamma[f] * rsqrtf(var + EPSV);
    bnp[f] = sc;
    bnp[128 + f] = beta[f] - mean * sc;
}

// ---------------------------------------------------------------------------
// pooling: batch is sorted; run-length accumulate, flush on graph change
// ---------------------------------------------------------------------------
__global__ __launch_bounds__(128) void pool_kernel(const float* __restrict__ h,
                                                   const int* __restrict__ batch,
                                                   float* __restrict__ gsum,
                                                   float* __restrict__ gcntf) {
    const int f = threadIdx.x;
    const int base = blockIdx.x * 512;
    const int end = (base + 512 < N_NODES) ? base + 512 : N_NODES;
    int cur = batch[base];
    float sum = 0.f, cnt = 0.f;
    for (int r = base; r < end; ++r) {
        int g = batch[r];
        if (g != cur) {
            atomicAdd(&gsum[cur * 128 + f], sum);
            if (f == 0) atomicAdd(&gcntf[cur], cnt);
            sum = 0.f; cnt = 0.f; cur = g;
        }
        sum += h[(size_t)r * 128 + f];
        cnt += 1.f;
    }
    atomicAdd(&gsum[cur * 128 + f], sum);
    if (f == 0) atomicAdd(&gcntf[cur], cnt);
}

__global__ void reps_kernel(const float* __restrict__ gsum,
                            const float* __restrict__ gcntf,
                            float* __restrict__ out_reps) {
    int i = blockIdx.x * 256 + threadIdx.x;
    if (i < NGRAPH * 128) {
        int g = i >> 7;
        out_reps[i] = gsum[i] / fmaxf(gcntf[g], 1.0f);
    }
}

// logits = relu(reps @ Wc1 + bc1) @ Wc2 + bc2, one block per graph
__global__ __launch_bounds__(128) void logits_kernel(
    const float* __restrict__ reps, const float* __restrict__ Wc1,
    const float* __restrict__ bc1, const float* __restrict__ Wc2,
    const float* __restrict__ bc2, float* __restrict__ out_logits) {
    __shared__ float repS[128];
    __shared__ float tmp[128];
    int g = blockIdx.x, t = threadIdx.x;
    repS[t] = reps[(size_t)g * 128 + t];
    __syncthreads();
    float acc = bc1[t];
    for (int k = 0; k < 128; ++k) acc = fmaf(repS[k], Wc1[k * 128 + t], acc);
    tmp[t] = fmaxf(acc, 0.f);
    __syncthreads();
    if (t < 2) {
        float a = bc2[t];
        for (int k = 0; k < 128; ++k) a = fmaf(tmp[k], Wc2[k * 2 + t], a);
        out_logits[g * 2 + t] = a;
    }
}

// ---------------------------------------------------------------------------
extern "C" void kernel_launch(void* const* d_in, const int* in_sizes, int n_in,
                              void* d_out, int out_size, void* d_ws, size_t ws_size,
                              hipStream_t stream) {
    const float* x      = (const float*)d_in[0];
    const int*   ei     = (const int*)d_in[1];
    const float* ea     = (const float*)d_in[2];
    const int*   batch  = (const int*)d_in[3];
    const float* Wg0    = (const float*)d_in[4];
    const float* bg0    = (const float*)d_in[5];
    const float* gamma0 = (const float*)d_in[6];
    const float* beta0  = (const float*)d_in[7];
    const float* Wg1    = (const float*)d_in[8];
    const float* bg1    = (const float*)d_in[9];
    const float* gamma1 = (const float*)d_in[10];
    const float* beta1  = (const float*)d_in[11];
    const float* Wl1    = (const float*)d_in[12];
    const float* bl1    = (const float*)d_in[13];
    const float* Wl2    = (const float*)d_in[14];
    const float* bl2    = (const float*)d_in[15];
    const float* Wc1    = (const float*)d_in[16];
    const float* bc1    = (const float*)d_in[17];
    const float* Wc2    = (const float*)d_in[18];
    const float* bc2    = (const float*)d_in[19];

    float* out = (float*)d_out;
    char* ws = (char*)d_ws;
    size_t off = 0;
    auto alloc = [&](size_t bytes) {
        void* p = ws + off;
        off += (bytes + 15) & ~(size_t)15;
        return p;
    };
    float* bufH   = (float*)alloc(sizeof(float) * (size_t)N_NODES * 128);
    float* bufA   = (float*)alloc(sizeof(float) * (size_t)N_NODES * 128);
    float* degv   = (float*)alloc(sizeof(float) * N_NODES);
    float* valv   = (float*)alloc(sizeof(float) * N_EDGES);
    int*   colIdx = (int*)alloc(sizeof(int) * N_EDGES);
    int*   cnt    = (int*)alloc(sizeof(int) * N_NODES);
    int*   fillc  = (int*)alloc(sizeof(int) * N_NODES);
    float* stats0 = (float*)alloc(sizeof(float) * 256);
    float* stats1 = (float*)alloc(sizeof(float) * 256);
    float* bnp0   = (float*)alloc(sizeof(float) * 256);
    float* bnp1   = (float*)alloc(sizeof(float) * 256);
    float* gsum   = (float*)alloc(sizeof(float) * NGRAPH * 128);
    float* gcntf  = (float*)alloc(sizeof(float) * NGRAPH);
    int*   rowptr = (int*)alloc(sizeof(int) * (N_NODES + 1));
    int*   blockSum = (int*)alloc(sizeof(int) * SCAN_BLOCKS);

    // graph structure (shared by both convs)
    init_kernel<<<(N_NODES + 255) / 256, 256, 0, stream>>>(degv, cnt, fillc, stats0,
                                                           stats1, gsum, gcntf);
    edge_deg_kernel<<<(N_EDGES + 255) / 256, 256, 0, stream>>>(ei, ea, degv, cnt);
    dinv_kernel<<<(N_NODES + 255) / 256, 256, 0, stream>>>(degv);
    scan1_kernel<<<SCAN_BLOCKS, 256, 0, stream>>>(cnt, blockSum);
    scan2_kernel<<<1, 512, 0, stream>>>(blockSum);
    scan3_kernel<<<SCAN_BLOCKS, 256, 0, stream>>>(cnt, blockSum, rowptr);
    fill_kernel<<<(N_EDGES + 255) / 256, 256, 0, stream>>>(ei, ea, degv, rowptr, fillc,
                                                           colIdx, valv);

    const int gemm_grid = (N_NODES + 63) / 64;
    const int agg_blocks = 2048;            // 8192 waves = full machine
    const int agg_nwaves = agg_blocks * 4;
    // conv0: H0 = x @ Wg0 ; h = relu(agg + bg0) ; BN0 stats
    gemm128_kernel<<<gemm_grid, 256, 0, stream>>>(x, Wg0, bufH, nullptr, nullptr, 0);
    agg_relu_kernel<<<agg_blocks, 256, 0, stream>>>(bufH, rowptr, colIdx, valv,
                                                    degv, bg0, bufA, stats0, agg_nwaves);
    bn_finalize_kernel<<<1, 128, 0, stream>>>(stats0, gamma0, beta0, bnp0);
    // conv1: H1 = bn(h) @ Wg1 ; h = relu(agg + bg1) ; BN1 stats
    gemm128_kernel<<<gemm_grid, 256, 0, stream>>>(bufA, Wg1, bufH, bnp0, nullptr, 0);
    agg_relu_kernel<<<agg_blocks, 256, 0, stream>>>(bufH, rowptr, colIdx, valv,
                                                    degv, bg1, bufA, stats1, agg_nwaves);
    bn_finalize_kernel<<<1, 128, 0, stream>>>(stats1, gamma1, beta1, bnp1);
    // lin1: relu(bn(h) @ Wl1 + bl1) ; lin2: @ Wl2 + bl2 -> d_out h
    gemm128_kernel<<<gemm_grid, 256, 0, stream>>>(bufA, Wl1, bufH, bnp1, bl1, 1);
    gemm128_kernel<<<gemm_grid, 256, 0, stream>>>(bufH, Wl2, out, nullptr, bl2, 0);
    // pooling + head
    pool_kernel<<<(N_NODES + 511) / 512, 128, 0, stream>>>(out, batch, gsum, gcntf);
    reps_kernel<<<(NGRAPH * 128 + 255) / 256, 256, 0, stream>>>(
        gsum, gcntf, out + (size_t)N_NODES * 128);
    logits_kernel<<<NGRAPH, 128, 0, stream>>>(out + (size_t)N_NODES * 128, Wc1, bc1, Wc2,
                                              bc2, out + (size_t)N_NODES * 128 + NGRAPH * 128);
}

// Round 4
// 871.227 us; speedup vs baseline: 1.5896x; 1.2880x over previous
//
#include <hip/hip_runtime.h>

#define N_NODES 100000
#define N_EDGES 1600000
#define DFEAT   128
#define NGRAPH  64
#define EPSV    1e-5f
#define SCAN_BLOCKS ((N_NODES + 255) / 256)   // 391

typedef float v4f  __attribute__((ext_vector_type(4)));
typedef short v8s  __attribute__((ext_vector_type(8)));   // 8 bf16 in 4 VGPRs
typedef unsigned short us4 __attribute__((ext_vector_type(4)));
typedef unsigned short us8 __attribute__((ext_vector_type(8)));

static __device__ __forceinline__ unsigned short f2bf(float f) {
    union { float f; unsigned int u; } v; v.f = f;
    unsigned int u = v.u;
    return (unsigned short)((u + 0x7FFFu + ((u >> 16) & 1u)) >> 16);   // RTNE
}
static __device__ __forceinline__ float bf2f(unsigned short b) {
    union { unsigned int u; float f; } v; v.u = ((unsigned int)b) << 16;
    return v.f;
}

// ---------------------------------------------------------------------------
// init: deg=1.0 (the +1.0 in reference), counters/stats/pool buffers = 0
// ---------------------------------------------------------------------------
__global__ void init_kernel(float* __restrict__ degv, int* __restrict__ cnt,
                            int* __restrict__ fillc, float* __restrict__ stats0,
                            float* __restrict__ stats1, float* __restrict__ gsum,
                            float* __restrict__ gcntf) {
    int i = blockIdx.x * 256 + threadIdx.x;
    if (i < N_NODES) { degv[i] = 1.0f; cnt[i] = 0; fillc[i] = 0; }
    if (i < 256)  { stats0[i] = 0.f; stats1[i] = 0.f; }
    if (i < NGRAPH * DFEAT) gsum[i] = 0.f;
    if (i < NGRAPH) gcntf[i] = 0.f;
}

// ---------------------------------------------------------------------------
// weight prep: Wt[n][k] = bf16(W[k][n]) for 4 weights (blockIdx>>6 selects)
// ---------------------------------------------------------------------------
__global__ __launch_bounds__(256) void wprep_kernel(
    const float* __restrict__ W0, const float* __restrict__ W1,
    const float* __restrict__ W2, const float* __restrict__ W3,
    unsigned short* __restrict__ T0, unsigned short* __restrict__ T1,
    unsigned short* __restrict__ T2, unsigned short* __restrict__ T3) {
    int which = blockIdx.x >> 6;
    int i = (blockIdx.x & 63) * 256 + threadIdx.x;   // 0..16383
    const float* W = which == 0 ? W0 : which == 1 ? W1 : which == 2 ? W2 : W3;
    unsigned short* T = which == 0 ? T0 : which == 1 ? T1 : which == 2 ? T2 : T3;
    int n = i >> 7, k = i & 127;
    T[n * 128 + k] = f2bf(W[k * 128 + n]);
}

// ---------------------------------------------------------------------------
// deg[dst] += w ; cnt[dst] += 1
// ---------------------------------------------------------------------------
__global__ void edge_deg_kernel(const int* __restrict__ ei, const float* __restrict__ ea,
                                float* __restrict__ degv, int* __restrict__ cnt) {
    int e = blockIdx.x * 256 + threadIdx.x;
    if (e >= N_EDGES) return;
    int d = ei[N_EDGES + e];
    float w = ea[2 * e + 1];
    atomicAdd(&degv[d], w);
    atomicAdd(&cnt[d], 1);
}

__global__ void dinv_kernel(float* __restrict__ degv) {
    int i = blockIdx.x * 256 + threadIdx.x;
    if (i < N_NODES) degv[i] = rsqrtf(degv[i]);
}

// ---------------------------------------------------------------------------
// 3-phase device-wide exclusive scan of cnt -> rowptr
// ---------------------------------------------------------------------------
__global__ __launch_bounds__(256) void scan1_kernel(const int* __restrict__ cnt,
                                                    int* __restrict__ blockSum) {
    __shared__ int lds[256];
    int i = blockIdx.x * 256 + threadIdx.x;
    int t = threadIdx.x;
    lds[t] = (i < N_NODES) ? cnt[i] : 0;
    __syncthreads();
    for (int off = 128; off > 0; off >>= 1) {
        if (t < off) lds[t] += lds[t + off];
        __syncthreads();
    }
    if (t == 0) blockSum[blockIdx.x] = lds[0];
}

__global__ __launch_bounds__(512) void scan2_kernel(int* __restrict__ blockSum) {
    __shared__ int lds[512];
    int t = threadIdx.x;
    int v = (t < SCAN_BLOCKS) ? blockSum[t] : 0;
    lds[t] = v;
    __syncthreads();
    for (int off = 1; off < 512; off <<= 1) {
        int u = (t >= off) ? lds[t - off] : 0;
        __syncthreads();
        lds[t] += u;
        __syncthreads();
    }
    if (t < SCAN_BLOCKS) blockSum[t] = lds[t] - v;  // exclusive
}

__global__ __launch_bounds__(256) void scan3_kernel(const int* __restrict__ cnt,
                                                    const int* __restrict__ blockSum,
                                                    int* __restrict__ rowptr) {
    __shared__ int lds[256];
    int i = blockIdx.x * 256 + threadIdx.x;
    int t = threadIdx.x;
    int v = (i < N_NODES) ? cnt[i] : 0;
    lds[t] = v;
    __syncthreads();
    for (int off = 1; off < 256; off <<= 1) {
        int u = (t >= off) ? lds[t - off] : 0;
        __syncthreads();
        lds[t] += u;
        __syncthreads();
    }
    if (i < N_NODES) rowptr[i] = blockSum[blockIdx.x] + lds[t] - v;
    if (i == 0) rowptr[N_NODES] = N_EDGES;
}

// ---------------------------------------------------------------------------
// fill CSR: col[pos]=src, val[pos]=dinv[src]*w*dinv[dst]
// ---------------------------------------------------------------------------
__global__ void fill_kernel(const int* __restrict__ ei, const float* __restrict__ ea,
                            const float* __restrict__ degv, const int* __restrict__ rowptr,
                            int* __restrict__ fillc, int* __restrict__ colIdx,
                            float* __restrict__ valv) {
    int e = blockIdx.x * 256 + threadIdx.x;
    if (e >= N_EDGES) return;
    int s = ei[e], d = ei[N_EDGES + e];
    float w = ea[2 * e + 1];
    float nrm = degv[s] * w * degv[d];
    int pos = rowptr[d] + atomicAdd(&fillc[d], 1);
    colIdx[pos] = s;
    valv[pos] = nrm;
}

// ---------------------------------------------------------------------------
// MFMA bf16 GEMM: Out[n x 128] = f(X) @ Wt^T (+bias)(+relu)
//   X: fp32 or bf16, f = optional per-col BN scale/shift (fp32)
//   Wt: [n][k] bf16 (pre-transposed). Out: bf16 or fp32.
// block 256 (4 waves), tile 128 rows; wave w owns rows [w*32, w*32+32)
// A/B frag: [m|n = lane&15][k = (lane>>4)*8 + j]; C/D: col=lane&15, row=(lane>>4)*4+reg
// ---------------------------------------------------------------------------
__global__ __launch_bounds__(256) void gemm_bf16_kernel(
    const void* __restrict__ Xv, int x_is_f32,
    const unsigned short* __restrict__ Wt,
    void* __restrict__ Outv, int out_is_f32,
    const float* __restrict__ bnp, const float* __restrict__ bias, int do_relu) {
    __shared__ unsigned short Xs[128][136];   // 34.8 KB (pad 8 -> stride 272B = free 2-way)
    __shared__ unsigned short Ws[128][136];
    const int tid = threadIdx.x;
    const int rb = blockIdx.x * 128;

    // stage Wt (32 KB): 64 ushorts per thread
#pragma unroll
    for (int it = 0; it < 8; ++it) {
        int flat = it * 2048 + tid * 8;
        int n = flat >> 7, k = flat & 127;
        *(us8*)&Ws[n][k] = *(const us8*)&Wt[n * 128 + k];
    }
    // stage X tile (BN applied on load, convert to bf16)
    if (x_is_f32) {
        const float* X = (const float*)Xv;
#pragma unroll
        for (int it = 0; it < 16; ++it) {
            int flat = it * 1024 + tid * 4;
            int r = flat >> 7, k = flat & 127;
            float4 v = make_float4(0.f, 0.f, 0.f, 0.f);
            if (rb + r < N_NODES) v = *(const float4*)&X[(size_t)(rb + r) * 128 + k];
            if (bnp) {
                v.x = v.x * bnp[k]     + bnp[128 + k];
                v.y = v.y * bnp[k + 1] + bnp[129 + k];
                v.z = v.z * bnp[k + 2] + bnp[130 + k];
                v.w = v.w * bnp[k + 3] + bnp[131 + k];
            }
            us4 o; o.x = f2bf(v.x); o.y = f2bf(v.y); o.z = f2bf(v.z); o.w = f2bf(v.w);
            *(us4*)&Xs[r][k] = o;
        }
    } else {
        const unsigned short* X = (const unsigned short*)Xv;
#pragma unroll
        for (int it = 0; it < 8; ++it) {
            int flat = it * 2048 + tid * 8;
            int r = flat >> 7, k = flat & 127;
            us8 v = {0, 0, 0, 0, 0, 0, 0, 0};
            if (rb + r < N_NODES) v = *(const us8*)&X[(size_t)(rb + r) * 128 + k];
            if (bnp) {
#pragma unroll
                for (int j = 0; j < 8; ++j)
                    v[j] = f2bf(bf2f(v[j]) * bnp[k + j] + bnp[128 + k + j]);
            }
            *(us8*)&Xs[r][k] = v;
        }
    }
    __syncthreads();

    const int wv = tid >> 6, lane = tid & 63;
    const int q = lane >> 4, c16 = lane & 15;
    v4f acc[2][8];
#pragma unroll
    for (int i = 0; i < 2; ++i)
#pragma unroll
        for (int j = 0; j < 8; ++j) acc[i][j] = (v4f){0.f, 0.f, 0.f, 0.f};

#pragma unroll
    for (int ks = 0; ks < 4; ++ks) {
        v8s a0 = *(const v8s*)&Xs[wv * 32 + c16][ks * 32 + q * 8];
        v8s a1 = *(const v8s*)&Xs[wv * 32 + 16 + c16][ks * 32 + q * 8];
#pragma unroll
        for (int nt = 0; nt < 8; ++nt) {
            v8s b = *(const v8s*)&Ws[nt * 16 + c16][ks * 32 + q * 8];
            acc[0][nt] = __builtin_amdgcn_mfma_f32_16x16x32_bf16(a0, b, acc[0][nt], 0, 0, 0);
            acc[1][nt] = __builtin_amdgcn_mfma_f32_16x16x32_bf16(a1, b, acc[1][nt], 0, 0, 0);
        }
    }

#pragma unroll
    for (int mt = 0; mt < 2; ++mt) {
#pragma unroll
        for (int nt = 0; nt < 8; ++nt) {
            int col = nt * 16 + c16;
            float bcol = bias ? bias[col] : 0.f;
#pragma unroll
            for (int r = 0; r < 4; ++r) {
                int row = rb + wv * 32 + mt * 16 + q * 4 + r;
                if (row >= N_NODES) continue;
                float o = acc[mt][nt][r] + bcol;
                if (do_relu) o = fmaxf(o, 0.f);
                if (out_is_f32) ((float*)Outv)[(size_t)row * 128 + col] = o;
                else ((unsigned short*)Outv)[(size_t)row * 128 + col] = f2bf(o);
            }
        }
    }
}

// ---------------------------------------------------------------------------
// aggregation (bf16 gather) + self term + bias + relu + BN stats (fp32)
// 1 wave/row, lane owns features {2*lane, 2*lane+1} packed in one uint
// ---------------------------------------------------------------------------
__global__ __launch_bounds__(256) void agg_relu_bf16_kernel(
    const unsigned short* __restrict__ H, const int* __restrict__ rowptr,
    const int* __restrict__ colIdx, const float* __restrict__ valv,
    const float* __restrict__ dinv, const float* __restrict__ bias,
    unsigned short* __restrict__ outb, float* __restrict__ stats, int nwaves) {
    __shared__ float red[1024];
    const int tid = threadIdx.x;
    const int wv = tid >> 6;
    const int lane = tid & 63;
    const float bx = bias[2 * lane], by = bias[2 * lane + 1];
    const unsigned int* __restrict__ H4 = (const unsigned int*)H;   // 64 uints/row
    unsigned int* __restrict__ O4 = (unsigned int*)outb;
    float s0 = 0.f, q0 = 0.f, s1 = 0.f, q1 = 0.f;

    for (int i = blockIdx.x * 4 + wv; i < N_NODES; i += nwaves) {
        int beg = __builtin_amdgcn_readfirstlane(rowptr[i]);
        int end = __builtin_amdgcn_readfirstlane(rowptr[i + 1]);
        float px0 = 0.f, py0 = 0.f, px1 = 0.f, py1 = 0.f;
        float px2 = 0.f, py2 = 0.f, px3 = 0.f, py3 = 0.f;
        int j = beg;
        for (; j + 4 <= end; j += 4) {
            int c0 = colIdx[j], c1 = colIdx[j + 1], c2 = colIdx[j + 2], c3 = colIdx[j + 3];
            float v0 = valv[j], v1 = valv[j + 1], v2 = valv[j + 2], v3 = valv[j + 3];
            unsigned int h0 = H4[(size_t)c0 * 64 + lane];
            unsigned int h1 = H4[(size_t)c1 * 64 + lane];
            unsigned int h2 = H4[(size_t)c2 * 64 + lane];
            unsigned int h3 = H4[(size_t)c3 * 64 + lane];
            px0 = fmaf(v0, bf2f((unsigned short)h0), px0);
            py0 = fmaf(v0, bf2f((unsigned short)(h0 >> 16)), py0);
            px1 = fmaf(v1, bf2f((unsigned short)h1), px1);
            py1 = fmaf(v1, bf2f((unsigned short)(h1 >> 16)), py1);
            px2 = fmaf(v2, bf2f((unsigned short)h2), px2);
            py2 = fmaf(v2, bf2f((unsigned short)(h2 >> 16)), py2);
            px3 = fmaf(v3, bf2f((unsigned short)h3), px3);
            py3 = fmaf(v3, bf2f((unsigned short)(h3 >> 16)), py3);
        }
        for (; j < end; ++j) {
            int c = colIdx[j];
            float v = valv[j];
            unsigned int h = H4[(size_t)c * 64 + lane];
            px0 = fmaf(v, bf2f((unsigned short)h), px0);
            py0 = fmaf(v, bf2f((unsigned short)(h >> 16)), py0);
        }
        float di = dinv[i];
        float dd = di * di;
        unsigned int hs = H4[(size_t)i * 64 + lane];
        float ax = (px0 + px1) + (px2 + px3);
        float ay = (py0 + py1) + (py2 + py3);
        ax = fmaf(dd, bf2f((unsigned short)hs), ax) + bx;
        ay = fmaf(dd, bf2f((unsigned short)(hs >> 16)), ay) + by;
        ax = fmaxf(ax, 0.f);
        ay = fmaxf(ay, 0.f);
        O4[(size_t)i * 64 + lane] =
            (unsigned int)f2bf(ax) | ((unsigned int)f2bf(ay) << 16);
        s0 += ax; q0 += ax * ax; s1 += ay; q1 += ay * ay;
    }

    red[wv * 128 + 2 * lane]           = s0;
    red[wv * 128 + 2 * lane + 1]       = s1;
    red[512 + wv * 128 + 2 * lane]     = q0;
    red[512 + wv * 128 + 2 * lane + 1] = q1;
    __syncthreads();
    if (tid < 128) {
        float ts = red[tid] + red[128 + tid] + red[256 + tid] + red[384 + tid];
        float tq = red[512 + tid] + red[640 + tid] + red[768 + tid] + red[896 + tid];
        atomicAdd(&stats[tid], ts);
        atomicAdd(&stats[128 + tid], tq);
    }
}

// stats -> per-feature scale/shift
__global__ void bn_finalize_kernel(const float* __restrict__ stats,
                                   const float* __restrict__ gamma,
                                   const float* __restrict__ beta,
                                   float* __restrict__ bnp) {
    int f = threadIdx.x;
    float mean = stats[f] / (float)N_NODES;
    float var = stats[128 + f] / (float)N_NODES - mean * mean;
    float sc = gamma[f] * rsqrtf(var + EPSV);
    bnp[f] = sc;
    bnp[128 + f] = beta[f] - mean * sc;
}

// ---------------------------------------------------------------------------
// pooling: batch is sorted; run-length accumulate, flush on graph change
// ---------------------------------------------------------------------------
__global__ __launch_bounds__(128) void pool_kernel(const float* __restrict__ h,
                                                   const int* __restrict__ batch,
                                                   float* __restrict__ gsum,
                                                   float* __restrict__ gcntf) {
    const int f = threadIdx.x;
    const int base = blockIdx.x * 512;
    const int end = (base + 512 < N_NODES) ? base + 512 : N_NODES;
    int cur = batch[base];
    float sum = 0.f, cnt = 0.f;
    for (int r = base; r < end; ++r) {
        int g = batch[r];
        if (g != cur) {
            atomicAdd(&gsum[cur * 128 + f], sum);
            if (f == 0) atomicAdd(&gcntf[cur], cnt);
            sum = 0.f; cnt = 0.f; cur = g;
        }
        sum += h[(size_t)r * 128 + f];
        cnt += 1.f;
    }
    atomicAdd(&gsum[cur * 128 + f], sum);
    if (f == 0) atomicAdd(&gcntf[cur], cnt);
}

__global__ void reps_kernel(const float* __restrict__ gsum,
                            const float* __restrict__ gcntf,
                            float* __restrict__ out_reps) {
    int i = blockIdx.x * 256 + threadIdx.x;
    if (i < NGRAPH * 128) {
        int g = i >> 7;
        out_reps[i] = gsum[i] / fmaxf(gcntf[g], 1.0f);
    }
}

__global__ __launch_bounds__(128) void logits_kernel(
    const float* __restrict__ reps, const float* __restrict__ Wc1,
    const float* __restrict__ bc1, const float* __restrict__ Wc2,
    const float* __restrict__ bc2, float* __restrict__ out_logits) {
    __shared__ float repS[128];
    __shared__ float tmp[128];
    int g = blockIdx.x, t = threadIdx.x;
    repS[t] = reps[(size_t)g * 128 + t];
    __syncthreads();
    float acc = bc1[t];
    for (int k = 0; k < 128; ++k) acc = fmaf(repS[k], Wc1[k * 128 + t], acc);
    tmp[t] = fmaxf(acc, 0.f);
    __syncthreads();
    if (t < 2) {
        float a = bc2[t];
        for (int k = 0; k < 128; ++k) a = fmaf(tmp[k], Wc2[k * 2 + t], a);
        out_logits[g * 2 + t] = a;
    }
}

// ---------------------------------------------------------------------------
extern "C" void kernel_launch(void* const* d_in, const int* in_sizes, int n_in,
                              void* d_out, int out_size, void* d_ws, size_t ws_size,
                              hipStream_t stream) {
    const float* x      = (const float*)d_in[0];
    const int*   ei     = (const int*)d_in[1];
    const float* ea     = (const float*)d_in[2];
    const int*   batch  = (const int*)d_in[3];
    const float* Wg0    = (const float*)d_in[4];
    const float* bg0    = (const float*)d_in[5];
    const float* gamma0 = (const float*)d_in[6];
    const float* beta0  = (const float*)d_in[7];
    const float* Wg1    = (const float*)d_in[8];
    const float* bg1    = (const float*)d_in[9];
    const float* gamma1 = (const float*)d_in[10];
    const float* beta1  = (const float*)d_in[11];
    const float* Wl1    = (const float*)d_in[12];
    const float* bl1    = (const float*)d_in[13];
    const float* Wl2    = (const float*)d_in[14];
    const float* bl2    = (const float*)d_in[15];
    const float* Wc1    = (const float*)d_in[16];
    const float* bc1    = (const float*)d_in[17];
    const float* Wc2    = (const float*)d_in[18];
    const float* bc2    = (const float*)d_in[19];

    float* out = (float*)d_out;
    char* ws = (char*)d_ws;
    size_t off = 0;
    auto alloc = [&](size_t bytes) {
        void* p = ws + off;
        off += (bytes + 15) & ~(size_t)15;
        return p;
    };
    unsigned short* bufHb = (unsigned short*)alloc(sizeof(unsigned short) * (size_t)N_NODES * 128);
    unsigned short* bufAb = (unsigned short*)alloc(sizeof(unsigned short) * (size_t)N_NODES * 128);
    unsigned short* Wt0   = (unsigned short*)alloc(sizeof(unsigned short) * 128 * 128);
    unsigned short* Wt1   = (unsigned short*)alloc(sizeof(unsigned short) * 128 * 128);
    unsigned short* Wt2   = (unsigned short*)alloc(sizeof(unsigned short) * 128 * 128);
    unsigned short* Wt3   = (unsigned short*)alloc(sizeof(unsigned short) * 128 * 128);
    float* degv   = (float*)alloc(sizeof(float) * N_NODES);
    float* valv   = (float*)alloc(sizeof(float) * N_EDGES);
    int*   colIdx = (int*)alloc(sizeof(int) * N_EDGES);
    int*   cnt    = (int*)alloc(sizeof(int) * N_NODES);
    int*   fillc  = (int*)alloc(sizeof(int) * N_NODES);
    float* stats0 = (float*)alloc(sizeof(float) * 256);
    float* stats1 = (float*)alloc(sizeof(float) * 256);
    float* bnp0   = (float*)alloc(sizeof(float) * 256);
    float* bnp1   = (float*)alloc(sizeof(float) * 256);
    float* gsum   = (float*)alloc(sizeof(float) * NGRAPH * 128);
    float* gcntf  = (float*)alloc(sizeof(float) * NGRAPH);
    int*   rowptr = (int*)alloc(sizeof(int) * (N_NODES + 1));
    int*   blockSum = (int*)alloc(sizeof(int) * SCAN_BLOCKS);

    // graph structure + weight prep
    init_kernel<<<(N_NODES + 255) / 256, 256, 0, stream>>>(degv, cnt, fillc, stats0,
                                                           stats1, gsum, gcntf);
    wprep_kernel<<<256, 256, 0, stream>>>(Wg0, Wg1, Wl1, Wl2, Wt0, Wt1, Wt2, Wt3);
    edge_deg_kernel<<<(N_EDGES + 255) / 256, 256, 0, stream>>>(ei, ea, degv, cnt);
    dinv_kernel<<<(N_NODES + 255) / 256, 256, 0, stream>>>(degv);
    scan1_kernel<<<SCAN_BLOCKS, 256, 0, stream>>>(cnt, blockSum);
    scan2_kernel<<<1, 512, 0, stream>>>(blockSum);
    scan3_kernel<<<SCAN_BLOCKS, 256, 0, stream>>>(cnt, blockSum, rowptr);
    fill_kernel<<<(N_EDGES + 255) / 256, 256, 0, stream>>>(ei, ea, degv, rowptr, fillc,
                                                           colIdx, valv);

    const int gemm_grid = (N_NODES + 127) / 128;   // 782
    const int agg_blocks = 2048;                   // 8192 waves
    const int agg_nwaves = agg_blocks * 4;
    // conv0: H0 = bf16(x) @ Wg0
    gemm_bf16_kernel<<<gemm_grid, 256, 0, stream>>>(x, 1, Wt0, bufHb, 0, nullptr, nullptr, 0);
    agg_relu_bf16_kernel<<<agg_blocks, 256, 0, stream>>>(bufHb, rowptr, colIdx, valv,
                                                         degv, bg0, bufAb, stats0, agg_nwaves);
    bn_finalize_kernel<<<1, 128, 0, stream>>>(stats0, gamma0, beta0, bnp0);
    // conv1: H1 = bn0(h) @ Wg1
    gemm_bf16_kernel<<<gemm_grid, 256, 0, stream>>>(bufAb, 0, Wt1, bufHb, 0, bnp0, nullptr, 0);
    agg_relu_bf16_kernel<<<agg_blocks, 256, 0, stream>>>(bufHb, rowptr, colIdx, valv,
                                                         degv, bg1, bufAb, stats1, agg_nwaves);
    bn_finalize_kernel<<<1, 128, 0, stream>>>(stats1, gamma1, beta1, bnp1);
    // lin1: relu(bn1(h) @ Wl1 + bl1) -> bf16 ; lin2: @ Wl2 + bl2 -> d_out fp32
    gemm_bf16_kernel<<<gemm_grid, 256, 0, stream>>>(bufAb, 0, Wt2, bufHb, 0, bnp1, bl1, 1);
    gemm_bf16_kernel<<<gemm_grid, 256, 0, stream>>>(bufHb, 0, Wt3, out, 1, nullptr, bl2, 0);
    // pooling + head
    pool_kernel<<<(N_NODES + 511) / 512, 128, 0, stream>>>(out, batch, gsum, gcntf);
    reps_kernel<<<(NGRAPH * 128 + 255) / 256, 256, 0, stream>>>(
        gsum, gcntf, out + (size_t)N_NODES * 128);
    logits_kernel<<<NGRAPH, 128, 0, stream>>>(out + (size_t)N_NODES * 128, Wc1, bc1, Wc2,
                                              bc2, out + (size_t)N_NODES * 128 + NGRAPH * 128);
}

// Round 5
// 799.049 us; speedup vs baseline: 1.7332x; 1.0903x over previous
//
#include <hip/hip_runtime.h>

#define N_NODES 100000
#define N_EDGES 1600000
#define DFEAT   128
#define NGRAPH  64
#define EPSV    1e-5f
#define SCAN_BLOCKS ((N_NODES + 255) / 256)   // 391
#define DEG_SCALE 268435456.0f                 // 2^28
#define DEG_MASK  ((1ULL << 42) - 1)

typedef float v4f  __attribute__((ext_vector_type(4)));
typedef short v8s  __attribute__((ext_vector_type(8)));   // 8 bf16 in 4 VGPRs
typedef unsigned short us4 __attribute__((ext_vector_type(4)));
typedef unsigned short us8 __attribute__((ext_vector_type(8)));

static __device__ __forceinline__ unsigned short f2bf(float f) {
    union { float f; unsigned int u; } v; v.f = f;
    unsigned int u = v.u;
    return (unsigned short)((u + 0x7FFFu + ((u >> 16) & 1u)) >> 16);   // RTNE
}
static __device__ __forceinline__ float bf2f(unsigned short b) {
    union { unsigned int u; float f; } v; v.u = ((unsigned int)b) << 16;
    return v.f;
}

// ---------------------------------------------------------------------------
// init: degcnt=0 (packed), fillc=0, stats/pool buffers = 0
// ---------------------------------------------------------------------------
__global__ void init_kernel(unsigned long long* __restrict__ degcnt,
                            int* __restrict__ fillc, float* __restrict__ stats0,
                            float* __restrict__ stats1, float* __restrict__ gsum,
                            float* __restrict__ gcntf) {
    int i = blockIdx.x * 256 + threadIdx.x;
    if (i < N_NODES) { degcnt[i] = 0ULL; fillc[i] = 0; }
    if (i < 256)  { stats0[i] = 0.f; stats1[i] = 0.f; }
    if (i < NGRAPH * DFEAT) gsum[i] = 0.f;
    if (i < NGRAPH) gcntf[i] = 0.f;
}

// ---------------------------------------------------------------------------
// weight prep: Wt[n][k] = bf16(W[k][n]) for 4 weights (blockIdx>>6 selects)
// ---------------------------------------------------------------------------
__global__ __launch_bounds__(256) void wprep_kernel(
    const float* __restrict__ W0, const float* __restrict__ W1,
    const float* __restrict__ W2, const float* __restrict__ W3,
    unsigned short* __restrict__ T0, unsigned short* __restrict__ T1,
    unsigned short* __restrict__ T2, unsigned short* __restrict__ T3) {
    int which = blockIdx.x >> 6;
    int i = (blockIdx.x & 63) * 256 + threadIdx.x;   // 0..16383
    const float* W = which == 0 ? W0 : which == 1 ? W1 : which == 2 ? W2 : W3;
    unsigned short* T = which == 0 ? T0 : which == 1 ? T1 : which == 2 ? T2 : T3;
    int n = i >> 7, k = i & 127;
    T[n * 128 + k] = f2bf(W[k * 128 + n]);
}

// ---------------------------------------------------------------------------
// ONE packed u64 atomic per edge: cnt in [42:63], fixed-point sum(w) in [0:41]
// ---------------------------------------------------------------------------
__global__ void edge_degcnt_kernel(const int* __restrict__ ei, const float* __restrict__ ea,
                                   unsigned long long* __restrict__ degcnt) {
    int e = blockIdx.x * 256 + threadIdx.x;
    if (e >= N_EDGES) return;
    int d = ei[N_EDGES + e];
    float w = ea[2 * e + 1];           // w in [0,1)
    unsigned long long v = (1ULL << 42) | (unsigned long long)(w * DEG_SCALE);
    atomicAdd(&degcnt[d], v);
}

// unpack: cnt[i] (for scan) and dinv[i] = rsqrt(1 + sum_w)
__global__ void dinv_kernel(const unsigned long long* __restrict__ degcnt,
                            int* __restrict__ cnt, float* __restrict__ dinv) {
    int i = blockIdx.x * 256 + threadIdx.x;
    if (i >= N_NODES) return;
    unsigned long long u = degcnt[i];
    cnt[i] = (int)(u >> 42);
    float deg = 1.0f + (float)(u & DEG_MASK) * (1.0f / DEG_SCALE);
    dinv[i] = rsqrtf(deg);
}

// ---------------------------------------------------------------------------
// 3-phase device-wide exclusive scan of cnt -> rowptr
// ---------------------------------------------------------------------------
__global__ __launch_bounds__(256) void scan1_kernel(const int* __restrict__ cnt,
                                                    int* __restrict__ blockSum) {
    __shared__ int lds[256];
    int i = blockIdx.x * 256 + threadIdx.x;
    int t = threadIdx.x;
    lds[t] = (i < N_NODES) ? cnt[i] : 0;
    __syncthreads();
    for (int off = 128; off > 0; off >>= 1) {
        if (t < off) lds[t] += lds[t + off];
        __syncthreads();
    }
    if (t == 0) blockSum[blockIdx.x] = lds[0];
}

__global__ __launch_bounds__(512) void scan2_kernel(int* __restrict__ blockSum) {
    __shared__ int lds[512];
    int t = threadIdx.x;
    int v = (t < SCAN_BLOCKS) ? blockSum[t] : 0;
    lds[t] = v;
    __syncthreads();
    for (int off = 1; off < 512; off <<= 1) {
        int u = (t >= off) ? lds[t - off] : 0;
        __syncthreads();
        lds[t] += u;
        __syncthreads();
    }
    if (t < SCAN_BLOCKS) blockSum[t] = lds[t] - v;  // exclusive
}

__global__ __launch_bounds__(256) void scan3_kernel(const int* __restrict__ cnt,
                                                    const int* __restrict__ blockSum,
                                                    int* __restrict__ rowptr) {
    __shared__ int lds[256];
    int i = blockIdx.x * 256 + threadIdx.x;
    int t = threadIdx.x;
    int v = (i < N_NODES) ? cnt[i] : 0;
    lds[t] = v;
    __syncthreads();
    for (int off = 1; off < 256; off <<= 1) {
        int u = (t >= off) ? lds[t - off] : 0;
        __syncthreads();
        lds[t] += u;
        __syncthreads();
    }
    if (i < N_NODES) rowptr[i] = blockSum[blockIdx.x] + lds[t] - v;
    if (i == 0) rowptr[N_NODES] = N_EDGES;
}

// ---------------------------------------------------------------------------
// fill CSR: edges[pos] = {src, bitcast(val)} in ONE 8B store
// ---------------------------------------------------------------------------
__global__ void fill_kernel(const int* __restrict__ ei, const float* __restrict__ ea,
                            const float* __restrict__ dinv, const int* __restrict__ rowptr,
                            int* __restrict__ fillc, int2* __restrict__ edges) {
    int e = blockIdx.x * 256 + threadIdx.x;
    if (e >= N_EDGES) return;
    int s = ei[e], d = ei[N_EDGES + e];
    float w = ea[2 * e + 1];
    float nrm = dinv[s] * w * dinv[d];
    int pos = rowptr[d] + atomicAdd(&fillc[d], 1);
    edges[pos] = make_int2(s, __float_as_int(nrm));
}

// ---------------------------------------------------------------------------
// MFMA bf16 GEMM: Out[n x 128] = f(X) @ Wt^T (+bias)(+relu)
// ---------------------------------------------------------------------------
__global__ __launch_bounds__(256) void gemm_bf16_kernel(
    const void* __restrict__ Xv, int x_is_f32,
    const unsigned short* __restrict__ Wt,
    void* __restrict__ Outv, int out_is_f32,
    const float* __restrict__ bnp, const float* __restrict__ bias, int do_relu) {
    __shared__ unsigned short Xs[128][136];
    __shared__ unsigned short Ws[128][136];
    const int tid = threadIdx.x;
    const int rb = blockIdx.x * 128;

#pragma unroll
    for (int it = 0; it < 8; ++it) {
        int flat = it * 2048 + tid * 8;
        int n = flat >> 7, k = flat & 127;
        *(us8*)&Ws[n][k] = *(const us8*)&Wt[n * 128 + k];
    }
    if (x_is_f32) {
        const float* X = (const float*)Xv;
#pragma unroll
        for (int it = 0; it < 16; ++it) {
            int flat = it * 1024 + tid * 4;
            int r = flat >> 7, k = flat & 127;
            float4 v = make_float4(0.f, 0.f, 0.f, 0.f);
            if (rb + r < N_NODES) v = *(const float4*)&X[(size_t)(rb + r) * 128 + k];
            if (bnp) {
                v.x = v.x * bnp[k]     + bnp[128 + k];
                v.y = v.y * bnp[k + 1] + bnp[129 + k];
                v.z = v.z * bnp[k + 2] + bnp[130 + k];
                v.w = v.w * bnp[k + 3] + bnp[131 + k];
            }
            us4 o; o.x = f2bf(v.x); o.y = f2bf(v.y); o.z = f2bf(v.z); o.w = f2bf(v.w);
            *(us4*)&Xs[r][k] = o;
        }
    } else {
        const unsigned short* X = (const unsigned short*)Xv;
#pragma unroll
        for (int it = 0; it < 8; ++it) {
            int flat = it * 2048 + tid * 8;
            int r = flat >> 7, k = flat & 127;
            us8 v = {0, 0, 0, 0, 0, 0, 0, 0};
            if (rb + r < N_NODES) v = *(const us8*)&X[(size_t)(rb + r) * 128 + k];
            if (bnp) {
#pragma unroll
                for (int j = 0; j < 8; ++j)
                    v[j] = f2bf(bf2f(v[j]) * bnp[k + j] + bnp[128 + k + j]);
            }
            *(us8*)&Xs[r][k] = v;
        }
    }
    __syncthreads();

    const int wv = tid >> 6, lane = tid & 63;
    const int q = lane >> 4, c16 = lane & 15;
    v4f acc[2][8];
#pragma unroll
    for (int i = 0; i < 2; ++i)
#pragma unroll
        for (int j = 0; j < 8; ++j) acc[i][j] = (v4f){0.f, 0.f, 0.f, 0.f};

#pragma unroll
    for (int ks = 0; ks < 4; ++ks) {
        v8s a0 = *(const v8s*)&Xs[wv * 32 + c16][ks * 32 + q * 8];
        v8s a1 = *(const v8s*)&Xs[wv * 32 + 16 + c16][ks * 32 + q * 8];
#pragma unroll
        for (int nt = 0; nt < 8; ++nt) {
            v8s b = *(const v8s*)&Ws[nt * 16 + c16][ks * 32 + q * 8];
            acc[0][nt] = __builtin_amdgcn_mfma_f32_16x16x32_bf16(a0, b, acc[0][nt], 0, 0, 0);
            acc[1][nt] = __builtin_amdgcn_mfma_f32_16x16x32_bf16(a1, b, acc[1][nt], 0, 0, 0);
        }
    }

#pragma unroll
    for (int mt = 0; mt < 2; ++mt) {
#pragma unroll
        for (int nt = 0; nt < 8; ++nt) {
            int col = nt * 16 + c16;
            float bcol = bias ? bias[col] : 0.f;
#pragma unroll
            for (int r = 0; r < 4; ++r) {
                int row = rb + wv * 32 + mt * 16 + q * 4 + r;
                if (row >= N_NODES) continue;
                float o = acc[mt][nt][r] + bcol;
                if (do_relu) o = fmaxf(o, 0.f);
                if (out_is_f32) ((float*)Outv)[(size_t)row * 128 + col] = o;
                else ((unsigned short*)Outv)[(size_t)row * 128 + col] = f2bf(o);
            }
        }
    }
}

// ---------------------------------------------------------------------------
// aggregation (bf16 gather) + self term + bias + relu + BN stats (fp32)
// 1 wave/row, lane owns features {2*lane, 2*lane+1}; edges as int2{src,val}
// ---------------------------------------------------------------------------
__global__ __launch_bounds__(256) void agg_relu_bf16_kernel(
    const unsigned short* __restrict__ H, const int* __restrict__ rowptr,
    const int2* __restrict__ edges,
    const float* __restrict__ dinv, const float* __restrict__ bias,
    unsigned short* __restrict__ outb, float* __restrict__ stats, int nwaves) {
    __shared__ float red[1024];
    const int tid = threadIdx.x;
    const int wv = tid >> 6;
    const int lane = tid & 63;
    const float bx = bias[2 * lane], by = bias[2 * lane + 1];
    const unsigned int* __restrict__ H4 = (const unsigned int*)H;   // 64 uints/row
    unsigned int* __restrict__ O4 = (unsigned int*)outb;
    float s0 = 0.f, q0 = 0.f, s1 = 0.f, q1 = 0.f;

    for (int i = blockIdx.x * 4 + wv; i < N_NODES; i += nwaves) {
        int beg = __builtin_amdgcn_readfirstlane(rowptr[i]);
        int end = __builtin_amdgcn_readfirstlane(rowptr[i + 1]);
        float px0 = 0.f, py0 = 0.f, px1 = 0.f, py1 = 0.f;
        float px2 = 0.f, py2 = 0.f, px3 = 0.f, py3 = 0.f;
        int j = beg;
        for (; j + 4 <= end; j += 4) {
            int2 e0 = edges[j], e1 = edges[j + 1], e2 = edges[j + 2], e3 = edges[j + 3];
            unsigned int h0 = H4[(size_t)e0.x * 64 + lane];
            unsigned int h1 = H4[(size_t)e1.x * 64 + lane];
            unsigned int h2 = H4[(size_t)e2.x * 64 + lane];
            unsigned int h3 = H4[(size_t)e3.x * 64 + lane];
            float v0 = __int_as_float(e0.y), v1 = __int_as_float(e1.y);
            float v2 = __int_as_float(e2.y), v3 = __int_as_float(e3.y);
            px0 = fmaf(v0, bf2f((unsigned short)h0), px0);
            py0 = fmaf(v0, bf2f((unsigned short)(h0 >> 16)), py0);
            px1 = fmaf(v1, bf2f((unsigned short)h1), px1);
            py1 = fmaf(v1, bf2f((unsigned short)(h1 >> 16)), py1);
            px2 = fmaf(v2, bf2f((unsigned short)h2), px2);
            py2 = fmaf(v2, bf2f((unsigned short)(h2 >> 16)), py2);
            px3 = fmaf(v3, bf2f((unsigned short)h3), px3);
            py3 = fmaf(v3, bf2f((unsigned short)(h3 >> 16)), py3);
        }
        for (; j < end; ++j) {
            int2 e0 = edges[j];
            float v = __int_as_float(e0.y);
            unsigned int h = H4[(size_t)e0.x * 64 + lane];
            px0 = fmaf(v, bf2f((unsigned short)h), px0);
            py0 = fmaf(v, bf2f((unsigned short)(h >> 16)), py0);
        }
        float di = dinv[i];
        float dd = di * di;
        unsigned int hs = H4[(size_t)i * 64 + lane];
        float ax = (px0 + px1) + (px2 + px3);
        float ay = (py0 + py1) + (py2 + py3);
        ax = fmaf(dd, bf2f((unsigned short)hs), ax) + bx;
        ay = fmaf(dd, bf2f((unsigned short)(hs >> 16)), ay) + by;
        ax = fmaxf(ax, 0.f);
        ay = fmaxf(ay, 0.f);
        O4[(size_t)i * 64 + lane] =
            (unsigned int)f2bf(ax) | ((unsigned int)f2bf(ay) << 16);
        s0 += ax; q0 += ax * ax; s1 += ay; q1 += ay * ay;
    }

    red[wv * 128 + 2 * lane]           = s0;
    red[wv * 128 + 2 * lane + 1]       = s1;
    red[512 + wv * 128 + 2 * lane]     = q0;
    red[512 + wv * 128 + 2 * lane + 1] = q1;
    __syncthreads();
    if (tid < 128) {
        float ts = red[tid] + red[128 + tid] + red[256 + tid] + red[384 + tid];
        float tq = red[512 + tid] + red[640 + tid] + red[768 + tid] + red[896 + tid];
        atomicAdd(&stats[tid], ts);
        atomicAdd(&stats[128 + tid], tq);
    }
}

// stats -> per-feature scale/shift
__global__ void bn_finalize_kernel(const float* __restrict__ stats,
                                   const float* __restrict__ gamma,
                                   const float* __restrict__ beta,
                                   float* __restrict__ bnp) {
    int f = threadIdx.x;
    float mean = stats[f] / (float)N_NODES;
    float var = stats[128 + f] / (float)N_NODES - mean * mean;
    float sc = gamma[f] * rsqrtf(var + EPSV);
    bnp[f] = sc;
    bnp[128 + f] = beta[f] - mean * sc;
}

// ---------------------------------------------------------------------------
// pooling: batch is sorted; run-length accumulate, flush on graph change
// ---------------------------------------------------------------------------
__global__ __launch_bounds__(128) void pool_kernel(const float* __restrict__ h,
                                                   const int* __restrict__ batch,
                                                   float* __restrict__ gsum,
                                                   float* __restrict__ gcntf) {
    const int f = threadIdx.x;
    const int base = blockIdx.x * 512;
    const int end = (base + 512 < N_NODES) ? base + 512 : N_NODES;
    int cur = batch[base];
    float sum = 0.f, cnt = 0.f;
    for (int r = base; r < end; ++r) {
        int g = batch[r];
        if (g != cur) {
            atomicAdd(&gsum[cur * 128 + f], sum);
            if (f == 0) atomicAdd(&gcntf[cur], cnt);
            sum = 0.f; cnt = 0.f; cur = g;
        }
        sum += h[(size_t)r * 128 + f];
        cnt += 1.f;
    }
    atomicAdd(&gsum[cur * 128 + f], sum);
    if (f == 0) atomicAdd(&gcntf[cur], cnt);
}

__global__ void reps_kernel(const float* __restrict__ gsum,
                            const float* __restrict__ gcntf,
                            float* __restrict__ out_reps) {
    int i = blockIdx.x * 256 + threadIdx.x;
    if (i < NGRAPH * 128) {
        int g = i >> 7;
        out_reps[i] = gsum[i] / fmaxf(gcntf[g], 1.0f);
    }
}

__global__ __launch_bounds__(128) void logits_kernel(
    const float* __restrict__ reps, const float* __restrict__ Wc1,
    const float* __restrict__ bc1, const float* __restrict__ Wc2,
    const float* __restrict__ bc2, float* __restrict__ out_logits) {
    __shared__ float repS[128];
    __shared__ float tmp[128];
    int g = blockIdx.x, t = threadIdx.x;
    repS[t] = reps[(size_t)g * 128 + t];
    __syncthreads();
    float acc = bc1[t];
    for (int k = 0; k < 128; ++k) acc = fmaf(repS[k], Wc1[k * 128 + t], acc);
    tmp[t] = fmaxf(acc, 0.f);
    __syncthreads();
    if (t < 2) {
        float a = bc2[t];
        for (int k = 0; k < 128; ++k) a = fmaf(tmp[k], Wc2[k * 2 + t], a);
        out_logits[g * 2 + t] = a;
    }
}

// ---------------------------------------------------------------------------
extern "C" void kernel_launch(void* const* d_in, const int* in_sizes, int n_in,
                              void* d_out, int out_size, void* d_ws, size_t ws_size,
                              hipStream_t stream) {
    const float* x      = (const float*)d_in[0];
    const int*   ei     = (const int*)d_in[1];
    const float* ea     = (const float*)d_in[2];
    const int*   batch  = (const int*)d_in[3];
    const float* Wg0    = (const float*)d_in[4];
    const float* bg0    = (const float*)d_in[5];
    const float* gamma0 = (const float*)d_in[6];
    const float* beta0  = (const float*)d_in[7];
    const float* Wg1    = (const float*)d_in[8];
    const float* bg1    = (const float*)d_in[9];
    const float* gamma1 = (const float*)d_in[10];
    const float* beta1  = (const float*)d_in[11];
    const float* Wl1    = (const float*)d_in[12];
    const float* bl1    = (const float*)d_in[13];
    const float* Wl2    = (const float*)d_in[14];
    const float* bl2    = (const float*)d_in[15];
    const float* Wc1    = (const float*)d_in[16];
    const float* bc1    = (const float*)d_in[17];
    const float* Wc2    = (const float*)d_in[18];
    const float* bc2    = (const float*)d_in[19];

    float* out = (float*)d_out;
    char* ws = (char*)d_ws;
    size_t off = 0;
    auto alloc = [&](size_t bytes) {
        void* p = ws + off;
        off += (bytes + 15) & ~(size_t)15;
        return p;
    };
    unsigned short* bufHb = (unsigned short*)alloc(sizeof(unsigned short) * (size_t)N_NODES * 128);
    unsigned short* bufAb = (unsigned short*)alloc(sizeof(unsigned short) * (size_t)N_NODES * 128);
    int2* edges = (int2*)alloc(sizeof(int2) * (size_t)N_EDGES);
    unsigned long long* degcnt = (unsigned long long*)alloc(sizeof(unsigned long long) * N_NODES);
    unsigned short* Wt0   = (unsigned short*)alloc(sizeof(unsigned short) * 128 * 128);
    unsigned short* Wt1   = (unsigned short*)alloc(sizeof(unsigned short) * 128 * 128);
    unsigned short* Wt2   = (unsigned short*)alloc(sizeof(unsigned short) * 128 * 128);
    unsigned short* Wt3   = (unsigned short*)alloc(sizeof(unsigned short) * 128 * 128);
    float* dinv   = (float*)alloc(sizeof(float) * N_NODES);
    int*   cnt    = (int*)alloc(sizeof(int) * N_NODES);
    int*   fillc  = (int*)alloc(sizeof(int) * N_NODES);
    float* stats0 = (float*)alloc(sizeof(float) * 256);
    float* stats1 = (float*)alloc(sizeof(float) * 256);
    float* bnp0   = (float*)alloc(sizeof(float) * 256);
    float* bnp1   = (float*)alloc(sizeof(float) * 256);
    float* gsum   = (float*)alloc(sizeof(float) * NGRAPH * 128);
    float* gcntf  = (float*)alloc(sizeof(float) * NGRAPH);
    int*   rowptr = (int*)alloc(sizeof(int) * (N_NODES + 1));
    int*   blockSum = (int*)alloc(sizeof(int) * SCAN_BLOCKS);

    // graph structure + weight prep
    init_kernel<<<(N_NODES + 255) / 256, 256, 0, stream>>>(degcnt, fillc, stats0,
                                                           stats1, gsum, gcntf);
    wprep_kernel<<<256, 256, 0, stream>>>(Wg0, Wg1, Wl1, Wl2, Wt0, Wt1, Wt2, Wt3);
    edge_degcnt_kernel<<<(N_EDGES + 255) / 256, 256, 0, stream>>>(ei, ea, degcnt);
    dinv_kernel<<<(N_NODES + 255) / 256, 256, 0, stream>>>(degcnt, cnt, dinv);
    scan1_kernel<<<SCAN_BLOCKS, 256, 0, stream>>>(cnt, blockSum);
    scan2_kernel<<<1, 512, 0, stream>>>(blockSum);
    scan3_kernel<<<SCAN_BLOCKS, 256, 0, stream>>>(cnt, blockSum, rowptr);
    fill_kernel<<<(N_EDGES + 255) / 256, 256, 0, stream>>>(ei, ea, dinv, rowptr, fillc,
                                                           edges);

    const int gemm_grid = (N_NODES + 127) / 128;   // 782
    const int agg_blocks = 2048;                   // 8192 waves
    const int agg_nwaves = agg_blocks * 4;
    // conv0: H0 = bf16(x) @ Wg0
    gemm_bf16_kernel<<<gemm_grid, 256, 0, stream>>>(x, 1, Wt0, bufHb, 0, nullptr, nullptr, 0);
    agg_relu_bf16_kernel<<<agg_blocks, 256, 0, stream>>>(bufHb, rowptr, edges,
                                                         dinv, bg0, bufAb, stats0, agg_nwaves);
    bn_finalize_kernel<<<1, 128, 0, stream>>>(stats0, gamma0, beta0, bnp0);
    // conv1: H1 = bn0(h) @ Wg1
    gemm_bf16_kernel<<<gemm_grid, 256, 0, stream>>>(bufAb, 0, Wt1, bufHb, 0, bnp0, nullptr, 0);
    agg_relu_bf16_kernel<<<agg_blocks, 256, 0, stream>>>(bufHb, rowptr, edges,
                                                         dinv, bg1, bufAb, stats1, agg_nwaves);
    bn_finalize_kernel<<<1, 128, 0, stream>>>(stats1, gamma1, beta1, bnp1);
    // lin1: relu(bn1(h) @ Wl1 + bl1) -> bf16 ; lin2: @ Wl2 + bl2 -> d_out fp32
    gemm_bf16_kernel<<<gemm_grid, 256, 0, stream>>>(bufAb, 0, Wt2, bufHb, 0, bnp1, bl1, 1);
    gemm_bf16_kernel<<<gemm_grid, 256, 0, stream>>>(bufHb, 0, Wt3, out, 1, nullptr, bl2, 0);
    // pooling + head
    pool_kernel<<<(N_NODES + 511) / 512, 128, 0, stream>>>(out, batch, gsum, gcntf);
    reps_kernel<<<(NGRAPH * 128 + 255) / 256, 256, 0, stream>>>(
        gsum, gcntf, out + (size_t)N_NODES * 128);
    logits_kernel<<<NGRAPH, 128, 0, stream>>>(out + (size_t)N_NODES * 128, Wc1, bc1, Wc2,
                                              bc2, out + (size_t)N_NODES * 128 + NGRAPH * 128);
}

// Round 6
// 692.495 us; speedup vs baseline: 1.9999x; 1.1539x over previous
//
#include <hip/hip_runtime.h>

#define N_NODES 100000
#define N_EDGES 1600000
#define DFEAT   128
#define NGRAPH  64
#define EPSV    1e-5f
#define SCAN_BLOCKS ((N_NODES + 255) / 256)   // 391
#define DEG_SCALE 268435456.0f                 // 2^28
#define DEG_MASK  ((1ULL << 42) - 1)

typedef float v4f  __attribute__((ext_vector_type(4)));
typedef short v8s  __attribute__((ext_vector_type(8)));   // 8 bf16 in 4 VGPRs
typedef unsigned short us4 __attribute__((ext_vector_type(4)));
typedef unsigned short us8 __attribute__((ext_vector_type(8)));

static __device__ __forceinline__ unsigned short f2bf(float f) {
    union { float f; unsigned int u; } v; v.f = f;
    unsigned int u = v.u;
    return (unsigned short)((u + 0x7FFFu + ((u >> 16) & 1u)) >> 16);   // RTNE
}
static __device__ __forceinline__ float bf2f(unsigned short b) {
    union { unsigned int u; float f; } v; v.u = ((unsigned int)b) << 16;
    return v.f;
}

// ---------------------------------------------------------------------------
// init: degcnt=0 (packed), fillc=0, stats/pool buffers = 0
// ---------------------------------------------------------------------------
__global__ void init_kernel(unsigned long long* __restrict__ degcnt,
                            int* __restrict__ fillc, float* __restrict__ stats0,
                            float* __restrict__ stats1, float* __restrict__ gsum,
                            float* __restrict__ gcntf) {
    int i = blockIdx.x * 256 + threadIdx.x;
    if (i < N_NODES) { degcnt[i] = 0ULL; fillc[i] = 0; }
    if (i < 256)  { stats0[i] = 0.f; stats1[i] = 0.f; }
    if (i < NGRAPH * DFEAT) gsum[i] = 0.f;
    if (i < NGRAPH) gcntf[i] = 0.f;
}

// ---------------------------------------------------------------------------
// weight prep: Wt[n][k] = bf16(W[k][n]) for 4 weights (blockIdx>>6 selects)
// ---------------------------------------------------------------------------
__global__ __launch_bounds__(256) void wprep_kernel(
    const float* __restrict__ W0, const float* __restrict__ W1,
    const float* __restrict__ W2, const float* __restrict__ W3,
    unsigned short* __restrict__ T0, unsigned short* __restrict__ T1,
    unsigned short* __restrict__ T2, unsigned short* __restrict__ T3) {
    int which = blockIdx.x >> 6;
    int i = (blockIdx.x & 63) * 256 + threadIdx.x;   // 0..16383
    const float* W = which == 0 ? W0 : which == 1 ? W1 : which == 2 ? W2 : W3;
    unsigned short* T = which == 0 ? T0 : which == 1 ? T1 : which == 2 ? T2 : T3;
    int n = i >> 7, k = i & 127;
    T[n * 128 + k] = f2bf(W[k * 128 + n]);
}

// ---------------------------------------------------------------------------
// ONE packed u64 atomic per edge: cnt in [42:63], fixed-point sum(w) in [0:41]
// ---------------------------------------------------------------------------
__global__ void edge_degcnt_kernel(const int* __restrict__ ei, const float* __restrict__ ea,
                                   unsigned long long* __restrict__ degcnt) {
    int e = blockIdx.x * 256 + threadIdx.x;
    if (e >= N_EDGES) return;
    int d = ei[N_EDGES + e];
    float w = ea[2 * e + 1];           // w in [0,1)
    unsigned long long v = (1ULL << 42) | (unsigned long long)(w * DEG_SCALE);
    atomicAdd(&degcnt[d], v);
}

// unpack: cnt[i] (for scan) and dinv[i] = rsqrt(1 + sum_w)
__global__ void dinv_kernel(const unsigned long long* __restrict__ degcnt,
                            int* __restrict__ cnt, float* __restrict__ dinv) {
    int i = blockIdx.x * 256 + threadIdx.x;
    if (i >= N_NODES) return;
    unsigned long long u = degcnt[i];
    cnt[i] = (int)(u >> 42);
    float deg = 1.0f + (float)(u & DEG_MASK) * (1.0f / DEG_SCALE);
    dinv[i] = rsqrtf(deg);
}

// ---------------------------------------------------------------------------
// 3-phase device-wide exclusive scan of cnt -> rowptr
// ---------------------------------------------------------------------------
__global__ __launch_bounds__(256) void scan1_kernel(const int* __restrict__ cnt,
                                                    int* __restrict__ blockSum) {
    __shared__ int lds[256];
    int i = blockIdx.x * 256 + threadIdx.x;
    int t = threadIdx.x;
    lds[t] = (i < N_NODES) ? cnt[i] : 0;
    __syncthreads();
    for (int off = 128; off > 0; off >>= 1) {
        if (t < off) lds[t] += lds[t + off];
        __syncthreads();
    }
    if (t == 0) blockSum[blockIdx.x] = lds[0];
}

__global__ __launch_bounds__(512) void scan2_kernel(int* __restrict__ blockSum) {
    __shared__ int lds[512];
    int t = threadIdx.x;
    int v = (t < SCAN_BLOCKS) ? blockSum[t] : 0;
    lds[t] = v;
    __syncthreads();
    for (int off = 1; off < 512; off <<= 1) {
        int u = (t >= off) ? lds[t - off] : 0;
        __syncthreads();
        lds[t] += u;
        __syncthreads();
    }
    if (t < SCAN_BLOCKS) blockSum[t] = lds[t] - v;  // exclusive
}

__global__ __launch_bounds__(256) void scan3_kernel(const int* __restrict__ cnt,
                                                    const int* __restrict__ blockSum,
                                                    int* __restrict__ rowptr) {
    __shared__ int lds[256];
    int i = blockIdx.x * 256 + threadIdx.x;
    int t = threadIdx.x;
    int v = (i < N_NODES) ? cnt[i] : 0;
    lds[t] = v;
    __syncthreads();
    for (int off = 1; off < 256; off <<= 1) {
        int u = (t >= off) ? lds[t - off] : 0;
        __syncthreads();
        lds[t] += u;
        __syncthreads();
    }
    if (i < N_NODES) rowptr[i] = blockSum[blockIdx.x] + lds[t] - v;
    if (i == 0) rowptr[N_NODES] = N_EDGES;
}

// ---------------------------------------------------------------------------
// fill CSR: edges[pos] = {src, bitcast(val)} in ONE 8B store
// ---------------------------------------------------------------------------
__global__ void fill_kernel(const int* __restrict__ ei, const float* __restrict__ ea,
                            const float* __restrict__ dinv, const int* __restrict__ rowptr,
                            int* __restrict__ fillc, int2* __restrict__ edges) {
    int e = blockIdx.x * 256 + threadIdx.x;
    if (e >= N_EDGES) return;
    int s = ei[e], d = ei[N_EDGES + e];
    float w = ea[2 * e + 1];
    float nrm = dinv[s] * w * dinv[d];
    int pos = rowptr[d] + atomicAdd(&fillc[d], 1);
    edges[pos] = make_int2(s, __float_as_int(nrm));
}

// ---------------------------------------------------------------------------
// MFMA bf16 GEMM: Out[n x 128] = f(X) @ Wt^T (+bias)(+relu)
// ---------------------------------------------------------------------------
__global__ __launch_bounds__(256) void gemm_bf16_kernel(
    const void* __restrict__ Xv, int x_is_f32,
    const unsigned short* __restrict__ Wt,
    void* __restrict__ Outv, int out_is_f32,
    const float* __restrict__ bnp, const float* __restrict__ bias, int do_relu) {
    __shared__ unsigned short Xs[128][136];
    __shared__ unsigned short Ws[128][136];
    const int tid = threadIdx.x;
    const int rb = blockIdx.x * 128;

#pragma unroll
    for (int it = 0; it < 8; ++it) {
        int flat = it * 2048 + tid * 8;
        int n = flat >> 7, k = flat & 127;
        *(us8*)&Ws[n][k] = *(const us8*)&Wt[n * 128 + k];
    }
    if (x_is_f32) {
        const float* X = (const float*)Xv;
#pragma unroll
        for (int it = 0; it < 16; ++it) {
            int flat = it * 1024 + tid * 4;
            int r = flat >> 7, k = flat & 127;
            float4 v = make_float4(0.f, 0.f, 0.f, 0.f);
            if (rb + r < N_NODES) v = *(const float4*)&X[(size_t)(rb + r) * 128 + k];
            if (bnp) {
                v.x = v.x * bnp[k]     + bnp[128 + k];
                v.y = v.y * bnp[k + 1] + bnp[129 + k];
                v.z = v.z * bnp[k + 2] + bnp[130 + k];
                v.w = v.w * bnp[k + 3] + bnp[131 + k];
            }
            us4 o; o.x = f2bf(v.x); o.y = f2bf(v.y); o.z = f2bf(v.z); o.w = f2bf(v.w);
            *(us4*)&Xs[r][k] = o;
        }
    } else {
        const unsigned short* X = (const unsigned short*)Xv;
#pragma unroll
        for (int it = 0; it < 8; ++it) {
            int flat = it * 2048 + tid * 8;
            int r = flat >> 7, k = flat & 127;
            us8 v = {0, 0, 0, 0, 0, 0, 0, 0};
            if (rb + r < N_NODES) v = *(const us8*)&X[(size_t)(rb + r) * 128 + k];
            if (bnp) {
#pragma unroll
                for (int j = 0; j < 8; ++j)
                    v[j] = f2bf(bf2f(v[j]) * bnp[k + j] + bnp[128 + k + j]);
            }
            *(us8*)&Xs[r][k] = v;
        }
    }
    __syncthreads();

    const int wv = tid >> 6, lane = tid & 63;
    const int q = lane >> 4, c16 = lane & 15;
    v4f acc[2][8];
#pragma unroll
    for (int i = 0; i < 2; ++i)
#pragma unroll
        for (int j = 0; j < 8; ++j) acc[i][j] = (v4f){0.f, 0.f, 0.f, 0.f};

#pragma unroll
    for (int ks = 0; ks < 4; ++ks) {
        v8s a0 = *(const v8s*)&Xs[wv * 32 + c16][ks * 32 + q * 8];
        v8s a1 = *(const v8s*)&Xs[wv * 32 + 16 + c16][ks * 32 + q * 8];
#pragma unroll
        for (int nt = 0; nt < 8; ++nt) {
            v8s b = *(const v8s*)&Ws[nt * 16 + c16][ks * 32 + q * 8];
            acc[0][nt] = __builtin_amdgcn_mfma_f32_16x16x32_bf16(a0, b, acc[0][nt], 0, 0, 0);
            acc[1][nt] = __builtin_amdgcn_mfma_f32_16x16x32_bf16(a1, b, acc[1][nt], 0, 0, 0);
        }
    }

#pragma unroll
    for (int mt = 0; mt < 2; ++mt) {
#pragma unroll
        for (int nt = 0; nt < 8; ++nt) {
            int col = nt * 16 + c16;
            float bcol = bias ? bias[col] : 0.f;
#pragma unroll
            for (int r = 0; r < 4; ++r) {
                int row = rb + wv * 32 + mt * 16 + q * 4 + r;
                if (row >= N_NODES) continue;
                float o = acc[mt][nt][r] + bcol;
                if (do_relu) o = fmaxf(o, 0.f);
                if (out_is_f32) ((float*)Outv)[(size_t)row * 128 + col] = o;
                else ((unsigned short*)Outv)[(size_t)row * 128 + col] = f2bf(o);
            }
        }
    }
}

// ---------------------------------------------------------------------------
// aggregation (bf16 gather) + self term + bias + relu + BN stats (fp32)
// 1 wave/row, lane owns features {2*lane, 2*lane+1}; edges as int2{src,val}
// ---------------------------------------------------------------------------
__global__ __launch_bounds__(256) void agg_relu_bf16_kernel(
    const unsigned short* __restrict__ H, const int* __restrict__ rowptr,
    const int2* __restrict__ edges,
    const float* __restrict__ dinv, const float* __restrict__ bias,
    unsigned short* __restrict__ outb, float* __restrict__ stats, int nwaves) {
    __shared__ float red[1024];
    const int tid = threadIdx.x;
    const int wv = tid >> 6;
    const int lane = tid & 63;
    const float bx = bias[2 * lane], by = bias[2 * lane + 1];
    const unsigned int* __restrict__ H4 = (const unsigned int*)H;   // 64 uints/row
    unsigned int* __restrict__ O4 = (unsigned int*)outb;
    float s0 = 0.f, q0 = 0.f, s1 = 0.f, q1 = 0.f;

    for (int i = blockIdx.x * 4 + wv; i < N_NODES; i += nwaves) {
        int beg = __builtin_amdgcn_readfirstlane(rowptr[i]);
        int end = __builtin_amdgcn_readfirstlane(rowptr[i + 1]);
        float px0 = 0.f, py0 = 0.f, px1 = 0.f, py1 = 0.f;
        float px2 = 0.f, py2 = 0.f, px3 = 0.f, py3 = 0.f;
        int j = beg;
        for (; j + 4 <= end; j += 4) {
            int2 e0 = edges[j], e1 = edges[j + 1], e2 = edges[j + 2], e3 = edges[j + 3];
            unsigned int h0 = H4[(size_t)e0.x * 64 + lane];
            unsigned int h1 = H4[(size_t)e1.x * 64 + lane];
            unsigned int h2 = H4[(size_t)e2.x * 64 + lane];
            unsigned int h3 = H4[(size_t)e3.x * 64 + lane];
            float v0 = __int_as_float(e0.y), v1 = __int_as_float(e1.y);
            float v2 = __int_as_float(e2.y), v3 = __int_as_float(e3.y);
            px0 = fmaf(v0, bf2f((unsigned short)h0), px0);
            py0 = fmaf(v0, bf2f((unsigned short)(h0 >> 16)), py0);
            px1 = fmaf(v1, bf2f((unsigned short)h1), px1);
            py1 = fmaf(v1, bf2f((unsigned short)(h1 >> 16)), py1);
            px2 = fmaf(v2, bf2f((unsigned short)h2), px2);
            py2 = fmaf(v2, bf2f((unsigned short)(h2 >> 16)), py2);
            px3 = fmaf(v3, bf2f((unsigned short)h3), px3);
            py3 = fmaf(v3, bf2f((unsigned short)(h3 >> 16)), py3);
        }
        for (; j < end; ++j) {
            int2 e0 = edges[j];
            float v = __int_as_float(e0.y);
            unsigned int h = H4[(size_t)e0.x * 64 + lane];
            px0 = fmaf(v, bf2f((unsigned short)h), px0);
            py0 = fmaf(v, bf2f((unsigned short)(h >> 16)), py0);
        }
        float di = dinv[i];
        float dd = di * di;
        unsigned int hs = H4[(size_t)i * 64 + lane];
        float ax = (px0 + px1) + (px2 + px3);
        float ay = (py0 + py1) + (py2 + py3);
        ax = fmaf(dd, bf2f((unsigned short)hs), ax) + bx;
        ay = fmaf(dd, bf2f((unsigned short)(hs >> 16)), ay) + by;
        ax = fmaxf(ax, 0.f);
        ay = fmaxf(ay, 0.f);
        O4[(size_t)i * 64 + lane] =
            (unsigned int)f2bf(ax) | ((unsigned int)f2bf(ay) << 16);
        s0 += ax; q0 += ax * ax; s1 += ay; q1 += ay * ay;
    }

    red[wv * 128 + 2 * lane]           = s0;
    red[wv * 128 + 2 * lane + 1]       = s1;
    red[512 + wv * 128 + 2 * lane]     = q0;
    red[512 + wv * 128 + 2 * lane + 1] = q1;
    __syncthreads();
    if (tid < 128) {
        float ts = red[tid] + red[128 + tid] + red[256 + tid] + red[384 + tid];
        float tq = red[512 + tid] + red[640 + tid] + red[768 + tid] + red[896 + tid];
        atomicAdd(&stats[tid], ts);
        atomicAdd(&stats[128 + tid], tq);
    }
}

// stats -> per-feature scale/shift
__global__ void bn_finalize_kernel(const float* __restrict__ stats,
                                   const float* __restrict__ gamma,
                                   const float* __restrict__ beta,
                                   float* __restrict__ bnp) {
    int f = threadIdx.x;
    float mean = stats[f] / (float)N_NODES;
    float var = stats[128 + f] / (float)N_NODES - mean * mean;
    float sc = gamma[f] * rsqrtf(var + EPSV);
    bnp[f] = sc;
    bnp[128 + f] = beta[f] - mean * sc;
}

// ---------------------------------------------------------------------------
// pooling: batch sorted; 128 rows/block, 256 threads = (feature, row-parity),
// run-length accumulate per thread, flush on graph change. ~12 waves/CU.
// ---------------------------------------------------------------------------
__global__ __launch_bounds__(256) void pool_kernel(const float* __restrict__ h,
                                                   const int* __restrict__ batch,
                                                   float* __restrict__ gsum,
                                                   float* __restrict__ gcntf) {
    const int f = threadIdx.x & 127;
    const int half = threadIdx.x >> 7;          // 0/1: even/odd rows
    const int base = blockIdx.x * 128;
    int r = base + half;
    const int end = (base + 128 < N_NODES) ? base + 128 : N_NODES;
    if (r >= end) return;
    int cur = batch[r];
    float sum = 0.f, cnt = 0.f;
    for (; r < end; r += 2) {
        int g = batch[r];
        if (g != cur) {
            atomicAdd(&gsum[cur * 128 + f], sum);
            if (f == 0) atomicAdd(&gcntf[cur], cnt);
            sum = 0.f; cnt = 0.f; cur = g;
        }
        sum += h[(size_t)r * 128 + f];
        cnt += 1.f;
    }
    atomicAdd(&gsum[cur * 128 + f], sum);
    if (f == 0) atomicAdd(&gcntf[cur], cnt);
}

__global__ void reps_kernel(const float* __restrict__ gsum,
                            const float* __restrict__ gcntf,
                            float* __restrict__ out_reps) {
    int i = blockIdx.x * 256 + threadIdx.x;
    if (i < NGRAPH * 128) {
        int g = i >> 7;
        out_reps[i] = gsum[i] / fmaxf(gcntf[g], 1.0f);
    }
}

__global__ __launch_bounds__(128) void logits_kernel(
    const float* __restrict__ reps, const float* __restrict__ Wc1,
    const float* __restrict__ bc1, const float* __restrict__ Wc2,
    const float* __restrict__ bc2, float* __restrict__ out_logits) {
    __shared__ float repS[128];
    __shared__ float tmp[128];
    int g = blockIdx.x, t = threadIdx.x;
    repS[t] = reps[(size_t)g * 128 + t];
    __syncthreads();
    float acc = bc1[t];
    for (int k = 0; k < 128; ++k) acc = fmaf(repS[k], Wc1[k * 128 + t], acc);
    tmp[t] = fmaxf(acc, 0.f);
    __syncthreads();
    if (t < 2) {
        float a = bc2[t];
        for (int k = 0; k < 128; ++k) a = fmaf(tmp[k], Wc2[k * 2 + t], a);
        out_logits[g * 2 + t] = a;
    }
}

// ---------------------------------------------------------------------------
extern "C" void kernel_launch(void* const* d_in, const int* in_sizes, int n_in,
                              void* d_out, int out_size, void* d_ws, size_t ws_size,
                              hipStream_t stream) {
    const float* x      = (const float*)d_in[0];
    const int*   ei     = (const int*)d_in[1];
    const float* ea     = (const float*)d_in[2];
    const int*   batch  = (const int*)d_in[3];
    const float* Wg0    = (const float*)d_in[4];
    const float* bg0    = (const float*)d_in[5];
    const float* gamma0 = (const float*)d_in[6];
    const float* beta0  = (const float*)d_in[7];
    const float* Wg1    = (const float*)d_in[8];
    const float* bg1    = (const float*)d_in[9];
    const float* gamma1 = (const float*)d_in[10];
    const float* beta1  = (const float*)d_in[11];
    const float* Wl1    = (const float*)d_in[12];
    const float* bl1    = (const float*)d_in[13];
    const float* Wl2    = (const float*)d_in[14];
    const float* bl2    = (const float*)d_in[15];
    const float* Wc1    = (const float*)d_in[16];
    const float* bc1    = (const float*)d_in[17];
    const float* Wc2    = (const float*)d_in[18];
    const float* bc2    = (const float*)d_in[19];

    float* out = (float*)d_out;
    char* ws = (char*)d_ws;
    size_t off = 0;
    auto alloc = [&](size_t bytes) {
        void* p = ws + off;
        off += (bytes + 15) & ~(size_t)15;
        return p;
    };
    unsigned short* bufHb = (unsigned short*)alloc(sizeof(unsigned short) * (size_t)N_NODES * 128);
    unsigned short* bufAb = (unsigned short*)alloc(sizeof(unsigned short) * (size_t)N_NODES * 128);
    int2* edges = (int2*)alloc(sizeof(int2) * (size_t)N_EDGES);
    unsigned long long* degcnt = (unsigned long long*)alloc(sizeof(unsigned long long) * N_NODES);
    unsigned short* Wt0   = (unsigned short*)alloc(sizeof(unsigned short) * 128 * 128);
    unsigned short* Wt1   = (unsigned short*)alloc(sizeof(unsigned short) * 128 * 128);
    unsigned short* Wt2   = (unsigned short*)alloc(sizeof(unsigned short) * 128 * 128);
    unsigned short* Wt3   = (unsigned short*)alloc(sizeof(unsigned short) * 128 * 128);
    float* dinv   = (float*)alloc(sizeof(float) * N_NODES);
    int*   cnt    = (int*)alloc(sizeof(int) * N_NODES);
    int*   fillc  = (int*)alloc(sizeof(int) * N_NODES);
    float* stats0 = (float*)alloc(sizeof(float) * 256);
    float* stats1 = (float*)alloc(sizeof(float) * 256);
    float* bnp0   = (float*)alloc(sizeof(float) * 256);
    float* bnp1   = (float*)alloc(sizeof(float) * 256);
    float* gsum   = (float*)alloc(sizeof(float) * NGRAPH * 128);
    float* gcntf  = (float*)alloc(sizeof(float) * NGRAPH);
    int*   rowptr = (int*)alloc(sizeof(int) * (N_NODES + 1));
    int*   blockSum = (int*)alloc(sizeof(int) * SCAN_BLOCKS);

    // graph structure + weight prep
    init_kernel<<<(N_NODES + 255) / 256, 256, 0, stream>>>(degcnt, fillc, stats0,
                                                           stats1, gsum, gcntf);
    wprep_kernel<<<256, 256, 0, stream>>>(Wg0, Wg1, Wl1, Wl2, Wt0, Wt1, Wt2, Wt3);
    edge_degcnt_kernel<<<(N_EDGES + 255) / 256, 256, 0, stream>>>(ei, ea, degcnt);
    dinv_kernel<<<(N_NODES + 255) / 256, 256, 0, stream>>>(degcnt, cnt, dinv);
    scan1_kernel<<<SCAN_BLOCKS, 256, 0, stream>>>(cnt, blockSum);
    scan2_kernel<<<1, 512, 0, stream>>>(blockSum);
    scan3_kernel<<<SCAN_BLOCKS, 256, 0, stream>>>(cnt, blockSum, rowptr);
    fill_kernel<<<(N_EDGES + 255) / 256, 256, 0, stream>>>(ei, ea, dinv, rowptr, fillc,
                                                           edges);

    const int gemm_grid = (N_NODES + 127) / 128;   // 782
    const int agg_blocks = 2048;                   // 8192 waves
    const int agg_nwaves = agg_blocks * 4;
    // conv0: H0 = bf16(x) @ Wg0
    gemm_bf16_kernel<<<gemm_grid, 256, 0, stream>>>(x, 1, Wt0, bufHb, 0, nullptr, nullptr, 0);
    agg_relu_bf16_kernel<<<agg_blocks, 256, 0, stream>>>(bufHb, rowptr, edges,
                                                         dinv, bg0, bufAb, stats0, agg_nwaves);
    bn_finalize_kernel<<<1, 128, 0, stream>>>(stats0, gamma0, beta0, bnp0);
    // conv1: H1 = bn0(h) @ Wg1
    gemm_bf16_kernel<<<gemm_grid, 256, 0, stream>>>(bufAb, 0, Wt1, bufHb, 0, bnp0, nullptr, 0);
    agg_relu_bf16_kernel<<<agg_blocks, 256, 0, stream>>>(bufHb, rowptr, edges,
                                                         dinv, bg1, bufAb, stats1, agg_nwaves);
    bn_finalize_kernel<<<1, 128, 0, stream>>>(stats1, gamma1, beta1, bnp1);
    // lin1: relu(bn1(h) @ Wl1 + bl1) -> bf16 ; lin2: @ Wl2 + bl2 -> d_out fp32
    gemm_bf16_kernel<<<gemm_grid, 256, 0, stream>>>(bufAb, 0, Wt2, bufHb, 0, bnp1, bl1, 1);
    gemm_bf16_kernel<<<gemm_grid, 256, 0, stream>>>(bufHb, 0, Wt3, out, 1, nullptr, bl2, 0);
    // pooling + head
    pool_kernel<<<(N_NODES + 127) / 128, 256, 0, stream>>>(out, batch, gsum, gcntf);
    reps_kernel<<<(NGRAPH * 128 + 255) / 256, 256, 0, stream>>>(
        gsum, gcntf, out + (size_t)N_NODES * 128);
    logits_kernel<<<NGRAPH, 128, 0, stream>>>(out + (size_t)N_NODES * 128, Wc1, bc1, Wc2,
                                              bc2, out + (size_t)N_NODES * 128 + NGRAPH * 128);
}